// Round 14
// baseline (273.441 us; speedup 1.0000x reference)
//
#include <hip/hip_runtime.h>
#include <hip/hip_bf16.h>
#include <math.h>

#define NF   128   // F
#define NPH  64    // PH
#define NP   8     // P
#define ND   4     // D
#define NH   128   // H
#define NC   10    // C
#define BCAP 2560  // 64-node bucket capacity (mean ~2046, 11 sigma slack)

typedef __bf16 bf16;
typedef __attribute__((ext_vector_type(4))) __bf16 bf16x4;
typedef __attribute__((ext_vector_type(8))) __bf16 bf16x8;
typedef __attribute__((ext_vector_type(4))) float f32x4;

// DPP rotate-reduce within each 16-lane row: pure VALU, no LDS.
template<int CTRL>
__device__ __forceinline__ float dpp_add(float x) {
    int t = __builtin_amdgcn_update_dpp(0, __float_as_int(x), CTRL, 0xf, 0xf, false);
    return x + __int_as_float(t);
}
__device__ __forceinline__ float row16_sum(float x) {
    x = dpp_add<0x121>(x);   // row_ror:1
    x = dpp_add<0x122>(x);   // row_ror:2
    x = dpp_add<0x124>(x);   // row_ror:4
    x = dpp_add<0x128>(x);   // row_ror:8
    return x;
}

// fast exact-erf GELU: Abramowitz-Stegun 7.1.25 (3-term), |eps|<=2.5e-5
__device__ __forceinline__ float gelu_fast(float x) {
    float z = fabsf(x) * 0.70710678118654752f;
    float t = __builtin_amdgcn_rcpf(1.0f + 0.47047f * z);
    float poly = t * (0.3480242f + t * (-0.0958798f + t * 0.7478556f));
    float erfv = 1.0f - poly * __expf(-z * z);
    float s = copysignf(erfv, x);
    return 0.5f * x * (1.0f + s);
}

#define GLOAD_LDS16(g, l)                                                     \
    __builtin_amdgcn_global_load_lds(                                         \
        (const __attribute__((address_space(1))) unsigned int*)(g),           \
        (__attribute__((address_space(3))) unsigned int*)(l), 16, 0, 0)

__device__ __forceinline__ bf16x8 cvt8(float4 a, float4 b) {
    bf16x8 r;
    r[0] = (bf16)a.x; r[1] = (bf16)a.y; r[2] = (bf16)a.z; r[3] = (bf16)a.w;
    r[4] = (bf16)b.x; r[5] = (bf16)b.y; r[6] = (bf16)b.z; r[7] = (bf16)b.w;
    return r;
}

// ---------------------------------------------------------------------------
// k_proj (MFMA): pp = x@W_proj.T + b_proj (bf16); h = gelu(x@W_x.T + b_x)
// ---------------------------------------------------------------------------
__global__ __launch_bounds__(256) void k_proj(
    const float* __restrict__ x,
    const float* __restrict__ Wproj, const float* __restrict__ bproj,
    const float* __restrict__ Wx,    const float* __restrict__ bx,
    bf16* __restrict__ pp, float* __restrict__ h, int N)
{
    __shared__ alignas(16) bf16 x_s[64 * 136];
    const int tid = threadIdx.x;
    const int w = tid >> 6, l = tid & 63;
    const int c = l & 15, g = l >> 4;

    bf16x8 bfr[3][4];
    float bias[3];
    #pragma unroll
    for (int t = 0; t < 3; ++t) {
        int ch = (w * 3 + t) * 16 + c;
        const float* wr = (ch < NPH) ? &Wproj[(size_t)ch * NF]
                                     : &Wx[(size_t)(ch - NPH) * NF];
        bias[t] = (ch < NPH) ? bproj[ch] : bx[ch - NPH];
        #pragma unroll
        for (int ks = 0; ks < 4; ++ks) {
            const float* src = wr + ks * 32 + g * 8;
            bfr[t][ks] = cvt8(*(const float4*)src, *(const float4*)(src + 4));
        }
    }

    const int n0 = blockIdx.x * 64;
    #pragma unroll
    for (int rr = 0; rr < 8; ++rr) {
        int id  = rr * 256 + tid;
        int row = id >> 5, c4 = id & 31;
        float4 v = make_float4(0.f, 0.f, 0.f, 0.f);
        if (n0 + row < N) v = *(const float4*)&x[(size_t)(n0 + row) * NF + c4 * 4];
        bf16x4 o;
        o[0] = (bf16)v.x; o[1] = (bf16)v.y; o[2] = (bf16)v.z; o[3] = (bf16)v.w;
        *(bf16x4*)&x_s[row * 136 + c4 * 4] = o;
    }
    __syncthreads();

    f32x4 acc[4][3] = {};
    #pragma unroll
    for (int rt = 0; rt < 4; ++rt)
        #pragma unroll
        for (int ks = 0; ks < 4; ++ks) {
            bf16x8 a = *(const bf16x8*)&x_s[(rt * 16 + c) * 136 + ks * 32 + g * 8];
            #pragma unroll
            for (int t = 0; t < 3; ++t)
                acc[rt][t] = __builtin_amdgcn_mfma_f32_16x16x32_bf16(
                    a, bfr[t][ks], acc[rt][t], 0, 0, 0);
        }

    #pragma unroll
    for (int rt = 0; rt < 4; ++rt) {
        #pragma unroll
        for (int t = 0; t < 3; ++t) {
            int ch = (w * 3 + t) * 16 + c;
            #pragma unroll
            for (int i = 0; i < 4; ++i) {
                int n = n0 + rt * 16 + g * 4 + i;
                if (n >= N) continue;
                float v = acc[rt][t][i] + bias[t];
                if (ch < NPH) pp[(size_t)n * NPH + ch] = (bf16)v;
                else          h[(size_t)n * NH + (ch - NPH)] = gelu_fast(v);
            }
        }
    }
}

// ---------------------------------------------------------------------------
// k_transpose: W_A [H,N] f32 -> Mb [N,H] bf16
// ---------------------------------------------------------------------------
__global__ __launch_bounds__(256) void k_transpose(
    const float* __restrict__ WA, bf16* __restrict__ Mb, int N)
{
    __shared__ float tt[128][65];
    const int n0  = blockIdx.x * 64;
    const int tid = threadIdx.x;
    const int w = tid >> 6, l = tid & 63;
    #pragma unroll
    for (int rep = 0; rep < 32; ++rep) {
        int hh = rep * 4 + w;
        int n  = n0 + l;
        tt[hh][l] = (n < N) ? WA[(size_t)hh * N + n] : 0.f;
    }
    __syncthreads();
    #pragma unroll
    for (int rep = 0; rep < 32; ++rep) {
        int n_l = rep * 2 + (tid >> 7);
        int n   = n0 + n_l;
        if (n < N) Mb[(size_t)n * NH + (tid & 127)] = (bf16)tt[tid & 127][n_l];
    }
}

// ---------------------------------------------------------------------------
// k_bucket: 2-pass counting bucket of edges by src>>6 into slack-offset
// packed u32 (src_local<<16 | dst). 4096-edge tiles. gcur sweep STAGGERED
// per-block so the global atomics don't hit the same line in lockstep.
// ---------------------------------------------------------------------------
__global__ __launch_bounds__(256) void k_bucket(
    const int* __restrict__ esrc, const int* __restrict__ edst,
    int* __restrict__ gcur, unsigned* __restrict__ pairs,
    int E, int nbuck)
{
    __shared__ int cnt[1024];
    __shared__ int bofs[1024];
    const int tid = threadIdx.x;
    const int tile = blockIdx.x * 4096;
    for (int i = tid; i < nbuck; i += 256) cnt[i] = 0;
    __syncthreads();
    #pragma unroll
    for (int k = 0; k < 16; ++k) {
        int i = tile + k * 256 + tid;
        if (i < E) atomicAdd(&cnt[esrc[i] >> 6], 1);
    }
    __syncthreads();
    // staggered sweep: bijection over [0,1024) per block, offset by block
    const unsigned off = ((unsigned)blockIdx.x * 197u) & 1023u;
    #pragma unroll
    for (int k = 0; k < 4; ++k) {
        int i = (int)(((unsigned)tid + 256u * (unsigned)k + off) & 1023u);
        if (i < nbuck) {
            int c = cnt[i];
            bofs[i] = c ? atomicAdd(&gcur[i], c) : 0;
            cnt[i] = 0;
        }
    }
    __syncthreads();
    #pragma unroll
    for (int k = 0; k < 16; ++k) {
        int i = tile + k * 256 + tid;
        if (i < E) {
            int s = esrc[i], b = s >> 6;
            int r = atomicAdd(&cnt[b], 1);
            pairs[(size_t)b * BCAP + bofs[b] + r] =
                ((unsigned)(s & 63) << 16) | (unsigned)edst[i];
        }
    }
}

// ---------------------------------------------------------------------------
// k_ax: channel-sliced A_x. bid = bucket*4 + ct; per-XCD working set
// Mb[:, ct*32..ct*32+31] = 3.2 MB < 4 MB L2. In-LDS bucket sort + gather.
// axbuf2 = 0.5*(A_x + bA).
// ---------------------------------------------------------------------------
__global__ __launch_bounds__(256) void k_ax(
    const unsigned* __restrict__ pairs, const int* __restrict__ gcur,
    const bf16* __restrict__ Mb, const float* __restrict__ bA,
    float* __restrict__ axbuf2, int N)
{
    __shared__ int hist[64], sc[64], cur[64];
    __shared__ unsigned short dstl[BCAP];
    const int bid = blockIdx.x;
    const int ct  = bid & 3;           // channel tile: 32 ch = 64 B
    const int b   = bid >> 2;          // bucket
    const int t   = threadIdx.x;
    const int cnt = gcur[b];
    const unsigned* pb = pairs + (size_t)b * BCAP;

    if (t < 64) hist[t] = 0;
    __syncthreads();
    for (int j = t; j < cnt; j += 256)
        atomicAdd(&hist[pb[j] >> 16], 1);
    __syncthreads();
    if (t < 64) sc[t] = hist[t];
    __syncthreads();
    for (int off = 1; off < 64; off <<= 1) {
        int u = (t < 64 && t >= off) ? sc[t - off] : 0;
        __syncthreads();
        if (t < 64) sc[t] += u;
        __syncthreads();
    }
    if (t < 64) cur[t] = sc[t] - hist[t];
    __syncthreads();
    for (int j = t; j < cnt; j += 256) {
        unsigned p = pb[j];
        int pos = atomicAdd(&cur[p >> 16], 1);
        dstl[pos] = (unsigned short)(p & 0xffffu);
    }
    __syncthreads();

    const int w = t >> 6, l = t & 63;
    const int e = l >> 4, q = l & 15;
    const unsigned* Mu32 = (const unsigned*)Mb;    // row = 64 dwords
    const int dwbase = ct * 16;
    const int chb = ct * 32;
    const int nb0 = b * 64;
    const float bA0 = bA[chb + q * 2];
    const float bA1 = bA[chb + q * 2 + 1];

    #pragma unroll 1
    for (int it = 0; it < 16; ++it) {
        const int node = it * 4 + w;
        const int hi2 = sc[node];
        int j = hi2 - hist[node];
        float a0 = 0.f, a1 = 0.f;
        for (; j + 16 <= hi2; j += 16) {
            int d0 = dstl[j + e], d1 = dstl[j + 4 + e];
            int d2 = dstl[j + 8 + e], d3 = dstl[j + 12 + e];
            unsigned v0 = Mu32[(size_t)d0 * 64 + dwbase + q];
            unsigned v1 = Mu32[(size_t)d1 * 64 + dwbase + q];
            unsigned v2 = Mu32[(size_t)d2 * 64 + dwbase + q];
            unsigned v3 = Mu32[(size_t)d3 * 64 + dwbase + q];
            a0 += __uint_as_float(v0 << 16) + __uint_as_float(v1 << 16) +
                  __uint_as_float(v2 << 16) + __uint_as_float(v3 << 16);
            a1 += __uint_as_float(v0 & 0xffff0000u) + __uint_as_float(v1 & 0xffff0000u) +
                  __uint_as_float(v2 & 0xffff0000u) + __uint_as_float(v3 & 0xffff0000u);
        }
        for (; j + 4 <= hi2; j += 4) {
            int d0 = dstl[j + e];
            unsigned v0 = Mu32[(size_t)d0 * 64 + dwbase + q];
            a0 += __uint_as_float(v0 << 16);
            a1 += __uint_as_float(v0 & 0xffff0000u);
        }
        if (j + e < hi2) {
            int d0 = dstl[j + e];
            unsigned v0 = Mu32[(size_t)d0 * 64 + dwbase + q];
            a0 += __uint_as_float(v0 << 16);
            a1 += __uint_as_float(v0 & 0xffff0000u);
        }
        a0 += __shfl_xor(a0, 16, 64);  a0 += __shfl_xor(a0, 32, 64);
        a1 += __shfl_xor(a1, 16, 64);  a1 += __shfl_xor(a1, 32, 64);
        const int n = nb0 + node;
        if (l < 16 && n < N) {
            float2 o;
            o.x = 0.5f * (a0 + bA0);
            o.y = 0.5f * (a1 + bA1);
            *(float2*)&axbuf2[(size_t)n * NH + chb + q * 2] = o;
        }
    }
}

// ---------------------------------------------------------------------------
// k_path: round-9 schedule + round-8 fused finale:
//   out = gelu(0.5*(pa + h) + axbuf2) @ Wend.T + bend
// ---------------------------------------------------------------------------
__global__ __launch_bounds__(256, 3) void k_path(
    const bf16* __restrict__ pp, const float* __restrict__ h,
    const float* __restrict__ Wpath, const float* __restrict__ bpath,
    const int* __restrict__ index, const float* __restrict__ axbuf2,
    const float* __restrict__ Wend, const float* __restrict__ bend,
    float* __restrict__ out, int N, int nrounds)
{
    __shared__ alignas(16) char smem[38144];
    bf16*  path_s = (bf16*)smem;                 // [2][32*256]  32768 B
    float* h_sf   = (float*)(smem + 32768);      // [2][4][128]   4096 B
    float* s_red  = (float*)(smem + 36864);      // [4][32]        512 B
    float* s_fin  = (float*)(smem + 37376);      // [4][4][12]     768 B

    const int tid = threadIdx.x;
    const int w   = tid >> 6;
    const int l   = tid & 63;
    const int c   = l & 15;
    const int g   = l >> 4;
    const int nl  = g >> 1;            // local node (within a pair)

    bf16x8 bfrag[2][8];
    #pragma unroll
    for (int ht = 0; ht < 2; ++ht) {
        int hg = (w * 2 + ht) * 16 + c;
        #pragma unroll
        for (int ks = 0; ks < 8; ++ks) {
            const float* src = &Wpath[(size_t)hg * 256 + ks * 32 + g * 8];
            bfrag[ht][ks] = cvt8(*(const float4*)src, *(const float4*)(src + 4));
        }
    }
    const float bp0 = bpath[(w * 2 + 0) * 16 + c];
    const float bp1 = bpath[(w * 2 + 1) * 16 + c];

    // hoist Wend columns for this lane's 2 channels
    float wendr[NC][2];
    #pragma unroll
    for (int cc = 0; cc < NC; ++cc) {
        wendr[cc][0] = Wend[cc * NH + w * 32 + c];
        wendr[cc][1] = Wend[cc * NH + w * 32 + 16 + c];
    }

    auto stage = [&](int round, int b) {
        const int n0 = round * 4;
        #pragma unroll
        for (int rr = 0; rr < 4; ++rr) {
            int id  = rr * 256 + tid;
            int row = id >> 5;
            int cc  = id & 31;
            int ls  = cc ^ (row & 7);      // source-side swizzle
            int d   = ls >> 3, q = ls & 7;
            int nn  = row >> 3, p = row & 7;
            int idx = index[(size_t)(n0 + nn) * (NP * ND) + p * ND + d];
            GLOAD_LDS16(pp + (size_t)idx * NPH + q * 8, &path_s[b * 8192 + id * 8]);
        }
        if (tid < 128) {
            int node = tid >> 5, q = tid & 31;
            GLOAD_LDS16(&h[(size_t)(n0 + node) * NH + q * 4],
                        &h_sf[(b * 4 + node) * 128 + q * 4]);
        }
    };

    int r = blockIdx.x;
    const int G = gridDim.x;
    if (r < nrounds) stage(r, 0);
    int buf = 0;

    for (; r < nrounds; r += G) {
        const int n0 = r * 4;
        __syncthreads();                        // round-r stage complete
        if (r + G < nrounds) stage(r + G, buf ^ 1);   // prefetch next round

        // prefetch this round's A_x contributions (used in finale)
        float axv[2][2];
        #pragma unroll
        for (int rt = 0; rt < 2; ++rt) {
            int n = n0 + rt * 2 + nl;
            axv[rt][0] = axbuf2[(size_t)n * NH + w * 32 + c];
            axv[rt][1] = axbuf2[(size_t)n * NH + w * 32 + 16 + c];
        }

        f32x4 acc[2][2] = {};
        #pragma unroll
        for (int rt = 0; rt < 2; ++rt) {
            const int rowbase = buf * 8192 + (rt * 16 + c) * 256;
            #pragma unroll
            for (int ks = 0; ks < 8; ++ks) {
                int chunk = (ks * 4 + g) ^ (c & 7);     // read-side XOR
                bf16x8 a = *(const bf16x8*)&path_s[rowbase + chunk * 8];
                acc[rt][0] = __builtin_amdgcn_mfma_f32_16x16x32_bf16(
                    a, bfrag[0][ks], acc[rt][0], 0, 0, 0);
                acc[rt][1] = __builtin_amdgcn_mfma_f32_16x16x32_bf16(
                    a, bfrag[1][ks], acc[rt][1], 0, 0, 0);
            }
        }

        // ep1: pi = gelu(acc+b); row-sums via DPP -> s_red
        float pi[2][2][4];
        float hvs[2][2];
        #pragma unroll
        for (int rt = 0; rt < 2; ++rt) {
            const float hv0 = h_sf[(buf * 4 + rt * 2 + nl) * 128 + w * 32 + c];
            const float hv1 = h_sf[(buf * 4 + rt * 2 + nl) * 128 + w * 32 + 16 + c];
            hvs[rt][0] = hv0; hvs[rt][1] = hv1;
            float sp[4];
            #pragma unroll
            for (int i = 0; i < 4; ++i) {
                pi[rt][0][i] = gelu_fast(acc[rt][0][i] + bp0);
                pi[rt][1][i] = gelu_fast(acc[rt][1][i] + bp1);
                sp[i] = hv0 * pi[rt][0][i] + hv1 * pi[rt][1][i];
            }
            #pragma unroll
            for (int i = 0; i < 4; ++i) sp[i] = row16_sum(sp[i]);
            float v = (c == 0) ? sp[0] : (c == 1) ? sp[1] : (c == 2) ? sp[2] : sp[3];
            if (c < 4) s_red[w * 32 + rt * 16 + g * 4 + c] = v;
        }

        // raw barrier #1: drain LDS only, keep global_load_lds in flight
        __builtin_amdgcn_sched_barrier(0);
        asm volatile("s_waitcnt lgkmcnt(0)" ::: "memory");
        __builtin_amdgcn_s_barrier();
        __builtin_amdgcn_sched_barrier(0);

        // ep2: softmax + agg + fused finale partials
        #pragma unroll
        for (int rt = 0; rt < 2; ++rt) {
            float4 r0 = *(const float4*)&s_red[0 * 32 + rt * 16 + g * 4];
            float4 r1 = *(const float4*)&s_red[1 * 32 + rt * 16 + g * 4];
            float4 r2 = *(const float4*)&s_red[2 * 32 + rt * 16 + g * 4];
            float4 r3 = *(const float4*)&s_red[3 * 32 + rt * 16 + g * 4];
            float st[4];
            st[0] = r0.x + r1.x + r2.x + r3.x;
            st[1] = r0.y + r1.y + r2.y + r3.y;
            st[2] = r0.z + r1.z + r2.z + r3.z;
            st[3] = r0.w + r1.w + r2.w + r3.w;
            float m4 = fmaxf(fmaxf(st[0], st[1]), fmaxf(st[2], st[3]));
            float m  = fmaxf(m4, __shfl_xor(m4, 16, 64));
            float e[4], s4 = 0.f;
            #pragma unroll
            for (int i = 0; i < 4; ++i) { e[i] = __expf(st[i] - m); s4 += e[i]; }
            float den = s4 + __shfl_xor(s4, 16, 64);
            const float inv = __builtin_amdgcn_rcpf(den);

            float pa0 = 0.f, pa1 = 0.f;
            #pragma unroll
            for (int i = 0; i < 4; ++i) {
                pa0 += e[i] * pi[rt][0][i];
                pa1 += e[i] * pi[rt][1][i];
            }
            pa0 = (pa0 + __shfl_xor(pa0, 16, 64)) * inv;
            pa1 = (pa1 + __shfl_xor(pa1, 16, 64)) * inv;

            // fused finale: val = 0.5(pa+h) + axbuf2; partial Wend dot
            float g0 = gelu_fast(0.5f * (pa0 + hvs[rt][0]) + axv[rt][0]);
            float g1 = gelu_fast(0.5f * (pa1 + hvs[rt][1]) + axv[rt][1]);
            float part[NC];
            #pragma unroll
            for (int cc = 0; cc < NC; ++cc)
                part[cc] = g0 * wendr[cc][0] + g1 * wendr[cc][1];
            #pragma unroll
            for (int cc = 0; cc < NC; ++cc) part[cc] = row16_sum(part[cc]);
            if (((g & 1) == 0) && c == 0) {
                float* dst = &s_fin[((rt * 2 + nl) * 4 + w) * 12];
                #pragma unroll
                for (int cc = 0; cc < NC; ++cc) dst[cc] = part[cc];
            }
        }

        // raw barrier #2: s_fin visibility (lgkm only)
        __builtin_amdgcn_sched_barrier(0);
        asm volatile("s_waitcnt lgkmcnt(0)" ::: "memory");
        __builtin_amdgcn_s_barrier();
        __builtin_amdgcn_sched_barrier(0);

        if (tid < 64) {
            int node = tid >> 4, idx = tid & 15;
            if (idx < NC) {
                float rs = s_fin[(node * 4 + 0) * 12 + idx]
                         + s_fin[(node * 4 + 1) * 12 + idx]
                         + s_fin[(node * 4 + 2) * 12 + idx]
                         + s_fin[(node * 4 + 3) * 12 + idx];
                out[(size_t)(n0 + node) * NC + idx] = rs + bend[idx];
            }
        }
        buf ^= 1;
    }
}

// ---------------------------------------------------------------------------
extern "C" void kernel_launch(void* const* d_in, const int* in_sizes, int n_in,
                              void* d_out, int out_size, void* d_ws, size_t ws_size,
                              hipStream_t stream)
{
    const float* x     = (const float*)d_in[0];
    const float* Wproj = (const float*)d_in[1];
    const float* bproj = (const float*)d_in[2];
    const float* Wx    = (const float*)d_in[3];
    const float* bx    = (const float*)d_in[4];
    const float* Wpath = (const float*)d_in[5];
    const float* bpath = (const float*)d_in[6];
    const float* WA    = (const float*)d_in[7];
    const float* bA    = (const float*)d_in[8];
    const float* Wend  = (const float*)d_in[9];
    const float* bend  = (const float*)d_in[10];
    const int*   index = (const int*)d_in[11];
    const int*   eidx  = (const int*)d_in[12];

    const int N = in_sizes[0] / NF;
    const int E = in_sizes[12] / 2;
    const int* esrc = eidx;
    const int* edst = eidx + E;
    const int nbuck = (N + 63) >> 6;     // 64-node buckets (needs N <= 65536)

    char* p = (char*)d_ws;
    auto alloc = [&](size_t bytes) {
        char* r = p;
        p += (bytes + 255) & ~(size_t)255;
        return r;
    };
    bf16*     pp     = (bf16*)alloc((size_t)N * NPH * sizeof(bf16));
    float*    h      = (float*)alloc((size_t)N * NH * sizeof(float));
    float*    axbuf2 = (float*)alloc((size_t)N * NH * sizeof(float));
    bf16*     Mb     = (bf16*)alloc((size_t)N * NH * sizeof(bf16));
    unsigned* pairs  = (unsigned*)alloc((size_t)nbuck * BCAP * sizeof(unsigned));
    int*      gcur   = (int*)alloc((size_t)nbuck * sizeof(int));

    const int nbP = (N + 63) / 64;
    const int nbT = (N + 63) / 64;
    const int nbB = (E + 4095) / 4096;
    const int NPATH = 1024;
    const int nrounds = N / 4;

    hipMemsetAsync(gcur, 0, (size_t)nbuck * sizeof(int), stream);
    k_proj<<<nbP, 256, 0, stream>>>(x, Wproj, bproj, Wx, bx, pp, h, N);
    k_transpose<<<nbT, 256, 0, stream>>>(WA, Mb, N);
    k_bucket<<<nbB, 256, 0, stream>>>(esrc, edst, gcur, pairs, E, nbuck);
    k_ax<<<nbuck * 4, 256, 0, stream>>>(pairs, gcur, Mb, bA, axbuf2, N);
    k_path<<<NPATH, 256, 0, stream>>>(pp, h, Wpath, bpath, index, axbuf2,
                                      Wend, bend, (float*)d_out, N, nrounds);
}

// Round 15
// 245.813 us; speedup vs baseline: 1.1124x; 1.1124x over previous
//
#include <hip/hip_runtime.h>
#include <hip/hip_bf16.h>
#include <math.h>

#define NF   128   // F
#define NPH  64    // PH
#define NP   8     // P
#define ND   4     // D
#define NH   128   // H
#define NC   10    // C
#define BCAP 2560  // 64-node bucket capacity (mean ~2046, 11 sigma slack)

typedef __bf16 bf16;
typedef __attribute__((ext_vector_type(4))) __bf16 bf16x4;
typedef __attribute__((ext_vector_type(8))) __bf16 bf16x8;
typedef __attribute__((ext_vector_type(4))) float f32x4;

// DPP rotate-reduce within each 16-lane row: pure VALU, no LDS.
template<int CTRL>
__device__ __forceinline__ float dpp_add(float x) {
    int t = __builtin_amdgcn_update_dpp(0, __float_as_int(x), CTRL, 0xf, 0xf, false);
    return x + __int_as_float(t);
}
__device__ __forceinline__ float row16_sum(float x) {
    x = dpp_add<0x121>(x);   // row_ror:1
    x = dpp_add<0x122>(x);   // row_ror:2
    x = dpp_add<0x124>(x);   // row_ror:4
    x = dpp_add<0x128>(x);   // row_ror:8
    return x;
}

// fast exact-erf GELU: Abramowitz-Stegun 7.1.25 (3-term), |eps|<=2.5e-5
__device__ __forceinline__ float gelu_fast(float x) {
    float z = fabsf(x) * 0.70710678118654752f;
    float t = __builtin_amdgcn_rcpf(1.0f + 0.47047f * z);
    float poly = t * (0.3480242f + t * (-0.0958798f + t * 0.7478556f));
    float erfv = 1.0f - poly * __expf(-z * z);
    float s = copysignf(erfv, x);
    return 0.5f * x * (1.0f + s);
}

#define GLOAD_LDS16(g, l)                                                     \
    __builtin_amdgcn_global_load_lds(                                         \
        (const __attribute__((address_space(1))) unsigned int*)(g),           \
        (__attribute__((address_space(3))) unsigned int*)(l), 16, 0, 0)

__device__ __forceinline__ bf16x8 cvt8(float4 a, float4 b) {
    bf16x8 r;
    r[0] = (bf16)a.x; r[1] = (bf16)a.y; r[2] = (bf16)a.z; r[3] = (bf16)a.w;
    r[4] = (bf16)b.x; r[5] = (bf16)b.y; r[6] = (bf16)b.z; r[7] = (bf16)b.w;
    return r;
}

__device__ __forceinline__ void add8(float* a, uint4 v) {
    a[0] += __uint_as_float(v.x << 16);  a[1] += __uint_as_float(v.x & 0xffff0000u);
    a[2] += __uint_as_float(v.y << 16);  a[3] += __uint_as_float(v.y & 0xffff0000u);
    a[4] += __uint_as_float(v.z << 16);  a[5] += __uint_as_float(v.z & 0xffff0000u);
    a[6] += __uint_as_float(v.w << 16);  a[7] += __uint_as_float(v.w & 0xffff0000u);
}

// ---------------------------------------------------------------------------
// k_front: fused [proj | transpose | bucket], parity-interleaved classes.
// ---------------------------------------------------------------------------
__global__ __launch_bounds__(256) void k_front(
    const float* __restrict__ x,
    const float* __restrict__ Wproj, const float* __restrict__ bproj,
    const float* __restrict__ Wx,    const float* __restrict__ bx,
    bf16* __restrict__ pp, float* __restrict__ h,
    const float* __restrict__ WA, bf16* __restrict__ Mb,
    const int* __restrict__ esrc, const int* __restrict__ edst,
    int* __restrict__ gcur, unsigned* __restrict__ pairs,
    int N, int E, int nbuck, int nbP, int nbT)
{
    __shared__ alignas(16) char smem[33280];
    const int tid = threadIdx.x;

    const int bid = blockIdx.x;
    const int two = 2 * nbP;
    int cls, idx;
    if (bid < two) { cls = bid & 1; idx = bid >> 1; }
    else           { cls = 1; idx = nbP + (bid - two); }

    if (cls == 0) {
        // ---------------- proj ----------------
        bf16* x_s = (bf16*)smem;                 // [64][136]
        const int w = tid >> 6, l = tid & 63;
        const int c = l & 15, g = l >> 4;

        bf16x8 bfr[3][4];
        float bias[3];
        #pragma unroll
        for (int t = 0; t < 3; ++t) {
            int ch = (w * 3 + t) * 16 + c;
            const float* wr = (ch < NPH) ? &Wproj[(size_t)ch * NF]
                                         : &Wx[(size_t)(ch - NPH) * NF];
            bias[t] = (ch < NPH) ? bproj[ch] : bx[ch - NPH];
            #pragma unroll
            for (int ks = 0; ks < 4; ++ks) {
                const float* src = wr + ks * 32 + g * 8;
                bfr[t][ks] = cvt8(*(const float4*)src, *(const float4*)(src + 4));
            }
        }

        const int n0 = idx * 64;
        #pragma unroll
        for (int rr = 0; rr < 8; ++rr) {
            int id  = rr * 256 + tid;
            int row = id >> 5, c4 = id & 31;
            float4 v = make_float4(0.f, 0.f, 0.f, 0.f);
            if (n0 + row < N) v = *(const float4*)&x[(size_t)(n0 + row) * NF + c4 * 4];
            bf16x4 o;
            o[0] = (bf16)v.x; o[1] = (bf16)v.y; o[2] = (bf16)v.z; o[3] = (bf16)v.w;
            *(bf16x4*)&x_s[row * 136 + c4 * 4] = o;
        }
        __syncthreads();

        f32x4 acc[4][3] = {};
        #pragma unroll
        for (int rt = 0; rt < 4; ++rt)
            #pragma unroll
            for (int ks = 0; ks < 4; ++ks) {
                bf16x8 a = *(const bf16x8*)&x_s[(rt * 16 + c) * 136 + ks * 32 + g * 8];
                #pragma unroll
                for (int t = 0; t < 3; ++t)
                    acc[rt][t] = __builtin_amdgcn_mfma_f32_16x16x32_bf16(
                        a, bfr[t][ks], acc[rt][t], 0, 0, 0);
            }

        #pragma unroll
        for (int rt = 0; rt < 4; ++rt) {
            #pragma unroll
            for (int t = 0; t < 3; ++t) {
                int ch = (w * 3 + t) * 16 + c;
                #pragma unroll
                for (int i = 0; i < 4; ++i) {
                    int n = n0 + rt * 16 + g * 4 + i;
                    if (n >= N) continue;
                    float v = acc[rt][t][i] + bias[t];
                    if (ch < NPH) pp[(size_t)n * NPH + ch] = (bf16)v;
                    else          h[(size_t)n * NH + (ch - NPH)] = gelu_fast(v);
                }
            }
        }
    } else if (idx < nbT) {
        // ---------------- transpose ----------------
        float* tt = (float*)smem;                // [128][65]
        const int n0 = idx * 64;
        const int w = tid >> 6, l = tid & 63;
        #pragma unroll
        for (int rep = 0; rep < 32; ++rep) {
            int hh = rep * 4 + w;
            int n  = n0 + l;
            tt[hh * 65 + l] = (n < N) ? WA[(size_t)hh * N + n] : 0.f;
        }
        __syncthreads();
        #pragma unroll
        for (int rep = 0; rep < 32; ++rep) {
            int n_l = rep * 2 + (tid >> 7);
            int n   = n0 + n_l;
            if (n < N) Mb[(size_t)n * NH + (tid & 127)] = (bf16)tt[(tid & 127) * 65 + n_l];
        }
    } else {
        // ---------------- bucket (2-pass, tile 4096 edges) ----------------
        int* cnt  = (int*)smem;          // [<=800]
        int* bofs = cnt + 800;
        const int tile = (idx - nbT) * 4096;
        for (int i = tid; i < nbuck; i += 256) cnt[i] = 0;
        __syncthreads();
        #pragma unroll
        for (int k = 0; k < 16; ++k) {
            int i = tile + k * 256 + tid;
            if (i < E) atomicAdd(&cnt[esrc[i] >> 6], 1);
        }
        __syncthreads();
        for (int i = tid; i < nbuck; i += 256) {
            int c = cnt[i];
            bofs[i] = c ? atomicAdd(&gcur[i], c) : 0;
            cnt[i] = 0;
        }
        __syncthreads();
        #pragma unroll
        for (int k = 0; k < 16; ++k) {
            int i = tile + k * 256 + tid;
            if (i < E) {
                int s = esrc[i], b = s >> 6;
                int r = atomicAdd(&cnt[b], 1);
                pairs[(size_t)b * BCAP + bofs[b] + r] =
                    ((unsigned)(s & 63) << 16) | (unsigned)edst[i];
            }
        }
    }
}

// ---------------------------------------------------------------------------
// k_mid2: fused [ax | path], parity-interleaved. launch_bounds(256,4):
// LDS 37376*4 = 149.5KB <= 160KB and VGPR 80 <= 128, so 4 blocks/CU fit —
// the (256,3) cap was leaving 33% of wave slots empty.
// ---------------------------------------------------------------------------
__global__ __launch_bounds__(256, 4) void k_mid2(
    const unsigned* __restrict__ pairs, const int* __restrict__ gcur,
    const bf16* __restrict__ Mb, const float* __restrict__ bA,
    float* __restrict__ axbuf2,
    const bf16* __restrict__ pp, const float* __restrict__ h,
    const float* __restrict__ Wpath, const float* __restrict__ bpath,
    const int* __restrict__ index, float* __restrict__ aggbuf,
    int N, int E, int nbuck, int nrounds)
{
    __shared__ alignas(16) char smem[37376];
    const int tid = threadIdx.x;

    // interleave: bid<2*nbuck: odd->ax, even->path; tail->path
    const int bid = blockIdx.x;
    const int two = 2 * nbuck;
    int cls, idx;
    if (bid < two) { cls = bid & 1; idx = bid >> 1; }
    else           { cls = 0; idx = nbuck + (bid - two); }

    if (cls == 1) {
        // ---------------- ax: in-LDS sort + gather (bucket idx) ----------------
        int* hist  = (int*)smem;                       // [64]
        int* sc    = hist + 64;                        // [64] inclusive scan
        int* cur   = hist + 128;                       // [64]
        unsigned short* dstl = (unsigned short*)(smem + 768);  // [BCAP]
        const int b = idx, t = tid;
        const int cnt = gcur[b];
        const unsigned* pb = pairs + (size_t)b * BCAP;

        if (t < 64) hist[t] = 0;
        __syncthreads();
        for (int j = t; j < cnt; j += 256)
            atomicAdd(&hist[pb[j] >> 16], 1);
        __syncthreads();
        if (t < 64) sc[t] = hist[t];
        __syncthreads();
        for (int off = 1; off < 64; off <<= 1) {
            int u = (t < 64 && t >= off) ? sc[t - off] : 0;
            __syncthreads();
            if (t < 64) sc[t] += u;
            __syncthreads();
        }
        if (t < 64) cur[t] = sc[t] - hist[t];          // exclusive base
        __syncthreads();
        for (int j = t; j < cnt; j += 256) {
            unsigned p = pb[j];
            int pos = atomicAdd(&cur[p >> 16], 1);
            dstl[pos] = (unsigned short)(p & 0xffffu);
        }
        __syncthreads();

        // gather: wave w handles nodes w, w+4, ... (16 per wave)
        const int w = t >> 6, l = t & 63;
        const int e = l >> 4, q = l & 15;
        const unsigned short* Mu = (const unsigned short*)Mb;
        const int nb0 = b * 64;
        #pragma unroll 1
        for (int it = 0; it < 16; ++it) {
            const int node = it * 4 + w;
            const int n = nb0 + node;
            const int le = sc[node];
            int j = le - hist[node];
            float acc[8] = {0.f, 0.f, 0.f, 0.f, 0.f, 0.f, 0.f, 0.f};
            for (; j + 32 <= le; j += 32) {
                int d[8];
                #pragma unroll
                for (int k = 0; k < 8; ++k) d[k] = dstl[j + k * 4 + e];
                uint4 v[8];
                #pragma unroll
                for (int k = 0; k < 8; ++k)
                    v[k] = *((const uint4*)(Mu + (size_t)d[k] * NH) + q);
                #pragma unroll
                for (int k = 0; k < 8; ++k) add8(acc, v[k]);
            }
            for (; j + 4 <= le; j += 4) {
                int d0 = dstl[j + e];
                uint4 v0 = *((const uint4*)(Mu + (size_t)d0 * NH) + q);
                add8(acc, v0);
            }
            if (e < le - j) {
                int d0 = dstl[j + e];
                uint4 v0 = *((const uint4*)(Mu + (size_t)d0 * NH) + q);
                add8(acc, v0);
            }
            #pragma unroll
            for (int k = 0; k < 8; ++k) {
                acc[k] += __shfl_xor(acc[k], 16, 64);
                acc[k] += __shfl_xor(acc[k], 32, 64);
            }
            if (l < 16 && n < N) {
                float4 bA0 = *(const float4*)&bA[q * 8];
                float4 bA1 = *(const float4*)&bA[q * 8 + 4];
                float4 o0 = make_float4(0.5f * (acc[0] + bA0.x), 0.5f * (acc[1] + bA0.y),
                                        0.5f * (acc[2] + bA0.z), 0.5f * (acc[3] + bA0.w));
                float4 o1 = make_float4(0.5f * (acc[4] + bA1.x), 0.5f * (acc[5] + bA1.y),
                                        0.5f * (acc[6] + bA1.z), 0.5f * (acc[7] + bA1.w));
                *(float4*)&axbuf2[(size_t)n * NH + q * 8]     = o0;
                *(float4*)&axbuf2[(size_t)n * NH + q * 8 + 4] = o1;
            }
        }
        return;
    }

    // ---------------- path (round-9 structure; block index = idx) ----------
    bf16*  path_s = (bf16*)smem;                 // [2][32*256]
    float* h_sf   = (float*)(smem + 32768);      // [2][4][128]
    float* s_red  = (float*)(smem + 36864);      // [4][32]

    const int w   = tid >> 6;
    const int l   = tid & 63;
    const int c   = l & 15;
    const int g   = l >> 4;
    const int nl  = g >> 1;            // local node (within a pair)

    bf16x8 bfrag[2][8];
    #pragma unroll
    for (int ht = 0; ht < 2; ++ht) {
        int hg = (w * 2 + ht) * 16 + c;
        #pragma unroll
        for (int ks = 0; ks < 8; ++ks) {
            const float* src = &Wpath[(size_t)hg * 256 + ks * 32 + g * 8];
            bfrag[ht][ks] = cvt8(*(const float4*)src, *(const float4*)(src + 4));
        }
    }
    const float bp0 = bpath[(w * 2 + 0) * 16 + c];
    const float bp1 = bpath[(w * 2 + 1) * 16 + c];

    auto stage = [&](int round, int b) {
        const int n0 = round * 4;
        #pragma unroll
        for (int rr = 0; rr < 4; ++rr) {
            int id  = rr * 256 + tid;
            int row = id >> 5;
            int cc  = id & 31;
            int ls  = cc ^ (row & 7);      // source-side swizzle
            int d   = ls >> 3, q = ls & 7;
            int nn  = row >> 3, p = row & 7;
            int idx2 = index[(size_t)(n0 + nn) * (NP * ND) + p * ND + d];
            GLOAD_LDS16(pp + (size_t)idx2 * NPH + q * 8, &path_s[b * 8192 + id * 8]);
        }
        if (tid < 128) {
            int node = tid >> 5, q = tid & 31;
            GLOAD_LDS16(&h[(size_t)(n0 + node) * NH + q * 4],
                        &h_sf[(b * 4 + node) * 128 + q * 4]);
        }
    };

    int r = idx;
    const int G = gridDim.x - nbuck;  // NPATH
    if (r < nrounds) stage(r, 0);
    int buf = 0;

    for (; r < nrounds; r += G) {
        const int n0 = r * 4;
        __syncthreads();                        // round-r stage complete
        if (r + G < nrounds) stage(r + G, buf ^ 1);   // prefetch next round

        f32x4 acc[2][2] = {};
        #pragma unroll
        for (int rt = 0; rt < 2; ++rt) {
            const int rowbase = buf * 8192 + (rt * 16 + c) * 256;
            #pragma unroll
            for (int ks = 0; ks < 8; ++ks) {
                int chunk = (ks * 4 + g) ^ (c & 7);     // read-side XOR
                bf16x8 a = *(const bf16x8*)&path_s[rowbase + chunk * 8];
                acc[rt][0] = __builtin_amdgcn_mfma_f32_16x16x32_bf16(
                    a, bfrag[0][ks], acc[rt][0], 0, 0, 0);
                acc[rt][1] = __builtin_amdgcn_mfma_f32_16x16x32_bf16(
                    a, bfrag[1][ks], acc[rt][1], 0, 0, 0);
            }
        }

        float pi[2][2][4];
        #pragma unroll
        for (int rt = 0; rt < 2; ++rt) {
            const float hv0 = h_sf[(buf * 4 + rt * 2 + nl) * 128 + w * 32 + c];
            const float hv1 = h_sf[(buf * 4 + rt * 2 + nl) * 128 + w * 32 + 16 + c];
            float sp[4];
            #pragma unroll
            for (int i = 0; i < 4; ++i) {
                pi[rt][0][i] = gelu_fast(acc[rt][0][i] + bp0);
                pi[rt][1][i] = gelu_fast(acc[rt][1][i] + bp1);
                sp[i] = hv0 * pi[rt][0][i] + hv1 * pi[rt][1][i];
            }
            #pragma unroll
            for (int i = 0; i < 4; ++i) sp[i] = row16_sum(sp[i]);
            float v = (c == 0) ? sp[0] : (c == 1) ? sp[1] : (c == 2) ? sp[2] : sp[3];
            if (c < 4) s_red[w * 32 + rt * 16 + g * 4 + c] = v;
        }

        __builtin_amdgcn_sched_barrier(0);
        asm volatile("s_waitcnt lgkmcnt(0)" ::: "memory");
        __builtin_amdgcn_s_barrier();
        __builtin_amdgcn_sched_barrier(0);

        #pragma unroll
        for (int rt = 0; rt < 2; ++rt) {
            float4 r0 = *(const float4*)&s_red[0 * 32 + rt * 16 + g * 4];
            float4 r1 = *(const float4*)&s_red[1 * 32 + rt * 16 + g * 4];
            float4 r2 = *(const float4*)&s_red[2 * 32 + rt * 16 + g * 4];
            float4 r3 = *(const float4*)&s_red[3 * 32 + rt * 16 + g * 4];
            float st[4];
            st[0] = r0.x + r1.x + r2.x + r3.x;
            st[1] = r0.y + r1.y + r2.y + r3.y;
            st[2] = r0.z + r1.z + r2.z + r3.z;
            st[3] = r0.w + r1.w + r2.w + r3.w;
            float m4 = fmaxf(fmaxf(st[0], st[1]), fmaxf(st[2], st[3]));
            float m  = fmaxf(m4, __shfl_xor(m4, 16, 64));
            float e[4], s4 = 0.f;
            #pragma unroll
            for (int i = 0; i < 4; ++i) { e[i] = __expf(st[i] - m); s4 += e[i]; }
            float den = s4 + __shfl_xor(s4, 16, 64);
            const float inv = __builtin_amdgcn_rcpf(den);

            float pa0 = 0.f, pa1 = 0.f;
            #pragma unroll
            for (int i = 0; i < 4; ++i) {
                pa0 += e[i] * pi[rt][0][i];
                pa1 += e[i] * pi[rt][1][i];
            }
            pa0 = (pa0 + __shfl_xor(pa0, 16, 64)) * inv;
            pa1 = (pa1 + __shfl_xor(pa1, 16, 64)) * inv;

            if (!(g & 1)) {
                int n = n0 + rt * 2 + nl;
                const float hv0 = h_sf[(buf * 4 + rt * 2 + nl) * 128 + w * 32 + c];
                const float hv1 = h_sf[(buf * 4 + rt * 2 + nl) * 128 + w * 32 + 16 + c];
                aggbuf[(size_t)n * NH + w * 32 + c]      = 0.5f * (pa0 + hv0);
                aggbuf[(size_t)n * NH + w * 32 + 16 + c] = 0.5f * (pa1 + hv1);
            }
        }
        buf ^= 1;
    }
}

// ---------------------------------------------------------------------------
// k_fin: out = gelu(aggbuf + axbuf2) @ Wend.T + bend  (memory-bound, ~51 MB)
// ---------------------------------------------------------------------------
__global__ __launch_bounds__(256) void k_fin(
    const float* __restrict__ aggbuf, const float* __restrict__ axbuf2,
    const float* __restrict__ Wend, const float* __restrict__ bend,
    float* __restrict__ out, int N)
{
    __shared__ float wend_s[NC][128];
    __shared__ float bend_s[NC];
    const int tid = threadIdx.x;
    for (int id = tid; id < NC * 128; id += 256) wend_s[id >> 7][id & 127] = Wend[id];
    if (tid < NC) bend_s[tid] = bend[tid];
    __syncthreads();

    const int w = tid >> 6, l = tid & 63;
    const int n = blockIdx.x * 4 + w;
    if (n >= N) return;
    const int q = l & 15;

    float4 agA = *(const float4*)&aggbuf[(size_t)n * NH + q * 8];
    float4 agB = *(const float4*)&aggbuf[(size_t)n * NH + q * 8 + 4];
    float4 axA = *(const float4*)&axbuf2[(size_t)n * NH + q * 8];
    float4 axB = *(const float4*)&axbuf2[(size_t)n * NH + q * 8 + 4];
    float gg[8];
    gg[0] = gelu_fast(agA.x + axA.x);
    gg[1] = gelu_fast(agA.y + axA.y);
    gg[2] = gelu_fast(agA.z + axA.z);
    gg[3] = gelu_fast(agA.w + axA.w);
    gg[4] = gelu_fast(agB.x + axB.x);
    gg[5] = gelu_fast(agB.y + axB.y);
    gg[6] = gelu_fast(agB.z + axB.z);
    gg[7] = gelu_fast(agB.w + axB.w);

    float part[NC];
    #pragma unroll
    for (int cc = 0; cc < NC; ++cc) {
        float p = 0.f;
        #pragma unroll
        for (int k = 0; k < 8; ++k) p += gg[k] * wend_s[cc][q * 8 + k];
        part[cc] = row16_sum(p);
    }

    float r = part[0];
    #pragma unroll
    for (int cc = 1; cc < NC; ++cc) r = (l == cc) ? part[cc] : r;
    if (l < NC) out[(size_t)n * NC + l] = r + bend_s[l];
}

// ---------------------------------------------------------------------------
extern "C" void kernel_launch(void* const* d_in, const int* in_sizes, int n_in,
                              void* d_out, int out_size, void* d_ws, size_t ws_size,
                              hipStream_t stream)
{
    const float* x     = (const float*)d_in[0];
    const float* Wproj = (const float*)d_in[1];
    const float* bproj = (const float*)d_in[2];
    const float* Wx    = (const float*)d_in[3];
    const float* bx    = (const float*)d_in[4];
    const float* Wpath = (const float*)d_in[5];
    const float* bpath = (const float*)d_in[6];
    const float* WA    = (const float*)d_in[7];
    const float* bA    = (const float*)d_in[8];
    const float* Wend  = (const float*)d_in[9];
    const float* bend  = (const float*)d_in[10];
    const int*   index = (const int*)d_in[11];
    const int*   eidx  = (const int*)d_in[12];

    const int N = in_sizes[0] / NF;
    const int E = in_sizes[12] / 2;
    const int* esrc = eidx;
    const int* edst = eidx + E;
    const int nbuck = (N + 63) >> 6;     // 64-node buckets (needs N <= 65536)

    char* p = (char*)d_ws;
    auto alloc = [&](size_t bytes) {
        char* r = p;
        p += (bytes + 255) & ~(size_t)255;
        return r;
    };
    bf16*     pp     = (bf16*)alloc((size_t)N * NPH * sizeof(bf16));
    float*    h      = (float*)alloc((size_t)N * NH * sizeof(float));
    float*    aggbuf = (float*)alloc((size_t)N * NH * sizeof(float));
    float*    axbuf2 = (float*)alloc((size_t)N * NH * sizeof(float));
    bf16*     Mb     = (bf16*)alloc((size_t)N * NH * sizeof(bf16));
    unsigned* pairs  = (unsigned*)alloc((size_t)nbuck * BCAP * sizeof(unsigned));
    int*      gcur   = (int*)alloc((size_t)nbuck * sizeof(int));

    const int nbP = (N + 63) / 64;
    const int nbT = (N + 63) / 64;
    const int nbB = (E + 4095) / 4096;
    const int NPATH = 1024;
    const int nrounds = N / 4;

    hipMemsetAsync(gcur, 0, (size_t)nbuck * sizeof(int), stream);
    k_front<<<nbP + nbT + nbB, 256, 0, stream>>>(
        x, Wproj, bproj, Wx, bx, pp, h, WA, Mb, esrc, edst, gcur, pairs,
        N, E, nbuck, nbP, nbT);
    k_mid2<<<nbuck + NPATH, 256, 0, stream>>>(
        pairs, gcur, Mb, bA, axbuf2, pp, h, Wpath, bpath, index, aggbuf,
        N, E, nbuck, nrounds);
    k_fin<<<(N + 3) / 4, 256, 0, stream>>>(aggbuf, axbuf2, Wend, bend,
                                           (float*)d_out, N);
}

// Round 16
// 232.055 us; speedup vs baseline: 1.1783x; 1.0593x over previous
//
#include <hip/hip_runtime.h>
#include <hip/hip_bf16.h>
#include <math.h>

#define NF   128   // F
#define NPH  64    // PH
#define NP   8     // P
#define ND   4     // D
#define NH   128   // H
#define NC   10    // C
#define BCAP 2560  // 64-node bucket capacity (mean ~2046, 11 sigma slack)

typedef __bf16 bf16;
typedef __attribute__((ext_vector_type(4))) __bf16 bf16x4;
typedef __attribute__((ext_vector_type(8))) __bf16 bf16x8;
typedef __attribute__((ext_vector_type(4))) float f32x4;

// DPP rotate-reduce within each 16-lane row: pure VALU, no LDS.
template<int CTRL>
__device__ __forceinline__ float dpp_add(float x) {
    int t = __builtin_amdgcn_update_dpp(0, __float_as_int(x), CTRL, 0xf, 0xf, false);
    return x + __int_as_float(t);
}
__device__ __forceinline__ float row16_sum(float x) {
    x = dpp_add<0x121>(x);   // row_ror:1
    x = dpp_add<0x122>(x);   // row_ror:2
    x = dpp_add<0x124>(x);   // row_ror:4
    x = dpp_add<0x128>(x);   // row_ror:8
    return x;
}

// fast exact-erf GELU: Abramowitz-Stegun 7.1.25 (3-term), |eps|<=2.5e-5
__device__ __forceinline__ float gelu_fast(float x) {
    float z = fabsf(x) * 0.70710678118654752f;
    float t = __builtin_amdgcn_rcpf(1.0f + 0.47047f * z);
    float poly = t * (0.3480242f + t * (-0.0958798f + t * 0.7478556f));
    float erfv = 1.0f - poly * __expf(-z * z);
    float s = copysignf(erfv, x);
    return 0.5f * x * (1.0f + s);
}

#define GLOAD_LDS16(g, l)                                                     \
    __builtin_amdgcn_global_load_lds(                                         \
        (const __attribute__((address_space(1))) unsigned int*)(g),           \
        (__attribute__((address_space(3))) unsigned int*)(l), 16, 0, 0)

__device__ __forceinline__ bf16x8 cvt8(float4 a, float4 b) {
    bf16x8 r;
    r[0] = (bf16)a.x; r[1] = (bf16)a.y; r[2] = (bf16)a.z; r[3] = (bf16)a.w;
    r[4] = (bf16)b.x; r[5] = (bf16)b.y; r[6] = (bf16)b.z; r[7] = (bf16)b.w;
    return r;
}

__device__ __forceinline__ void add8(float* a, uint4 v) {
    a[0] += __uint_as_float(v.x << 16);  a[1] += __uint_as_float(v.x & 0xffff0000u);
    a[2] += __uint_as_float(v.y << 16);  a[3] += __uint_as_float(v.y & 0xffff0000u);
    a[4] += __uint_as_float(v.z << 16);  a[5] += __uint_as_float(v.z & 0xffff0000u);
    a[6] += __uint_as_float(v.w << 16);  a[7] += __uint_as_float(v.w & 0xffff0000u);
}

// ---------------------------------------------------------------------------
// k_front: fused [proj | transpose | bucket], parity-interleaved classes.
// h stored bf16 (halves h write+read traffic; error budget has 4x headroom).
// ---------------------------------------------------------------------------
__global__ __launch_bounds__(256) void k_front(
    const float* __restrict__ x,
    const float* __restrict__ Wproj, const float* __restrict__ bproj,
    const float* __restrict__ Wx,    const float* __restrict__ bx,
    bf16* __restrict__ pp, bf16* __restrict__ hb,
    const float* __restrict__ WA, bf16* __restrict__ Mb,
    const int* __restrict__ esrc, const int* __restrict__ edst,
    int* __restrict__ gcur, unsigned* __restrict__ pairs,
    int N, int E, int nbuck, int nbP, int nbT)
{
    __shared__ alignas(16) char smem[33280];
    const int tid = threadIdx.x;

    const int bid = blockIdx.x;
    const int two = 2 * nbP;
    int cls, idx;
    if (bid < two) { cls = bid & 1; idx = bid >> 1; }
    else           { cls = 1; idx = nbP + (bid - two); }

    if (cls == 0) {
        // ---------------- proj ----------------
        bf16* x_s = (bf16*)smem;                 // [64][136]
        const int w = tid >> 6, l = tid & 63;
        const int c = l & 15, g = l >> 4;

        bf16x8 bfr[3][4];
        float bias[3];
        #pragma unroll
        for (int t = 0; t < 3; ++t) {
            int ch = (w * 3 + t) * 16 + c;
            const float* wr = (ch < NPH) ? &Wproj[(size_t)ch * NF]
                                         : &Wx[(size_t)(ch - NPH) * NF];
            bias[t] = (ch < NPH) ? bproj[ch] : bx[ch - NPH];
            #pragma unroll
            for (int ks = 0; ks < 4; ++ks) {
                const float* src = wr + ks * 32 + g * 8;
                bfr[t][ks] = cvt8(*(const float4*)src, *(const float4*)(src + 4));
            }
        }

        const int n0 = idx * 64;
        #pragma unroll
        for (int rr = 0; rr < 8; ++rr) {
            int id  = rr * 256 + tid;
            int row = id >> 5, c4 = id & 31;
            float4 v = make_float4(0.f, 0.f, 0.f, 0.f);
            if (n0 + row < N) v = *(const float4*)&x[(size_t)(n0 + row) * NF + c4 * 4];
            bf16x4 o;
            o[0] = (bf16)v.x; o[1] = (bf16)v.y; o[2] = (bf16)v.z; o[3] = (bf16)v.w;
            *(bf16x4*)&x_s[row * 136 + c4 * 4] = o;
        }
        __syncthreads();

        f32x4 acc[4][3] = {};
        #pragma unroll
        for (int rt = 0; rt < 4; ++rt)
            #pragma unroll
            for (int ks = 0; ks < 4; ++ks) {
                bf16x8 a = *(const bf16x8*)&x_s[(rt * 16 + c) * 136 + ks * 32 + g * 8];
                #pragma unroll
                for (int t = 0; t < 3; ++t)
                    acc[rt][t] = __builtin_amdgcn_mfma_f32_16x16x32_bf16(
                        a, bfr[t][ks], acc[rt][t], 0, 0, 0);
            }

        #pragma unroll
        for (int rt = 0; rt < 4; ++rt) {
            #pragma unroll
            for (int t = 0; t < 3; ++t) {
                int ch = (w * 3 + t) * 16 + c;
                #pragma unroll
                for (int i = 0; i < 4; ++i) {
                    int n = n0 + rt * 16 + g * 4 + i;
                    if (n >= N) continue;
                    float v = acc[rt][t][i] + bias[t];
                    if (ch < NPH) pp[(size_t)n * NPH + ch] = (bf16)v;
                    else          hb[(size_t)n * NH + (ch - NPH)] = (bf16)gelu_fast(v);
                }
            }
        }
    } else if (idx < nbT) {
        // ---------------- transpose ----------------
        float* tt = (float*)smem;                // [128][65]
        const int n0 = idx * 64;
        const int w = tid >> 6, l = tid & 63;
        #pragma unroll
        for (int rep = 0; rep < 32; ++rep) {
            int hh = rep * 4 + w;
            int n  = n0 + l;
            tt[hh * 65 + l] = (n < N) ? WA[(size_t)hh * N + n] : 0.f;
        }
        __syncthreads();
        #pragma unroll
        for (int rep = 0; rep < 32; ++rep) {
            int n_l = rep * 2 + (tid >> 7);
            int n   = n0 + n_l;
            if (n < N) Mb[(size_t)n * NH + (tid & 127)] = (bf16)tt[(tid & 127) * 65 + n_l];
        }
    } else {
        // ---------------- bucket (2-pass, tile 4096 edges) ----------------
        int* cnt  = (int*)smem;          // [<=800]
        int* bofs = cnt + 800;
        const int tile = (idx - nbT) * 4096;
        for (int i = tid; i < nbuck; i += 256) cnt[i] = 0;
        __syncthreads();
        #pragma unroll
        for (int k = 0; k < 16; ++k) {
            int i = tile + k * 256 + tid;
            if (i < E) atomicAdd(&cnt[esrc[i] >> 6], 1);
        }
        __syncthreads();
        for (int i = tid; i < nbuck; i += 256) {
            int c = cnt[i];
            bofs[i] = c ? atomicAdd(&gcur[i], c) : 0;
            cnt[i] = 0;
        }
        __syncthreads();
        #pragma unroll
        for (int k = 0; k < 16; ++k) {
            int i = tile + k * 256 + tid;
            if (i < E) {
                int s = esrc[i], b = s >> 6;
                int r = atomicAdd(&cnt[b], 1);
                pairs[(size_t)b * BCAP + bofs[b] + r] =
                    ((unsigned)(s & 63) << 16) | (unsigned)edst[i];
            }
        }
    }
}

// ---------------------------------------------------------------------------
// k_mid2: fused [ax | path], parity-interleaved, launch_bounds(256,3)
// (the proven round-11 configuration; (256,4) measured worse — L2 thrash).
// ---------------------------------------------------------------------------
__global__ __launch_bounds__(256, 3) void k_mid2(
    const unsigned* __restrict__ pairs, const int* __restrict__ gcur,
    const bf16* __restrict__ Mb, const float* __restrict__ bA,
    float* __restrict__ axbuf2,
    const bf16* __restrict__ pp, const bf16* __restrict__ hb,
    const float* __restrict__ Wpath, const float* __restrict__ bpath,
    const int* __restrict__ index, float* __restrict__ aggbuf,
    int N, int E, int nbuck, int nrounds)
{
    __shared__ alignas(16) char smem[35328];
    const int tid = threadIdx.x;

    // interleave: bid<2*nbuck: odd->ax, even->path; tail->path
    const int bid = blockIdx.x;
    const int two = 2 * nbuck;
    int cls, idx;
    if (bid < two) { cls = bid & 1; idx = bid >> 1; }
    else           { cls = 0; idx = nbuck + (bid - two); }

    if (cls == 1) {
        // ---------------- ax: in-LDS sort + gather (bucket idx) ----------------
        int* hist  = (int*)smem;                       // [64]
        int* sc    = hist + 64;                        // [64] inclusive scan
        int* cur   = hist + 128;                       // [64]
        unsigned short* dstl = (unsigned short*)(smem + 768);  // [BCAP]
        const int b = idx, t = tid;
        const int cnt = gcur[b];
        const unsigned* pb = pairs + (size_t)b * BCAP;

        if (t < 64) hist[t] = 0;
        __syncthreads();
        for (int j = t; j < cnt; j += 256)
            atomicAdd(&hist[pb[j] >> 16], 1);
        __syncthreads();
        if (t < 64) sc[t] = hist[t];
        __syncthreads();
        for (int off = 1; off < 64; off <<= 1) {
            int u = (t < 64 && t >= off) ? sc[t - off] : 0;
            __syncthreads();
            if (t < 64) sc[t] += u;
            __syncthreads();
        }
        if (t < 64) cur[t] = sc[t] - hist[t];          // exclusive base
        __syncthreads();
        for (int j = t; j < cnt; j += 256) {
            unsigned p = pb[j];
            int pos = atomicAdd(&cur[p >> 16], 1);
            dstl[pos] = (unsigned short)(p & 0xffffu);
        }
        __syncthreads();

        // gather: wave w handles nodes w, w+4, ... (16 per wave)
        const int w = t >> 6, l = t & 63;
        const int e = l >> 4, q = l & 15;
        const unsigned short* Mu = (const unsigned short*)Mb;
        const int nb0 = b * 64;
        #pragma unroll 1
        for (int it = 0; it < 16; ++it) {
            const int node = it * 4 + w;
            const int n = nb0 + node;
            const int le = sc[node];
            int j = le - hist[node];
            float acc[8] = {0.f, 0.f, 0.f, 0.f, 0.f, 0.f, 0.f, 0.f};
            for (; j + 32 <= le; j += 32) {
                int d[8];
                #pragma unroll
                for (int k = 0; k < 8; ++k) d[k] = dstl[j + k * 4 + e];
                uint4 v[8];
                #pragma unroll
                for (int k = 0; k < 8; ++k)
                    v[k] = *((const uint4*)(Mu + (size_t)d[k] * NH) + q);
                #pragma unroll
                for (int k = 0; k < 8; ++k) add8(acc, v[k]);
            }
            for (; j + 4 <= le; j += 4) {
                int d0 = dstl[j + e];
                uint4 v0 = *((const uint4*)(Mu + (size_t)d0 * NH) + q);
                add8(acc, v0);
            }
            if (e < le - j) {
                int d0 = dstl[j + e];
                uint4 v0 = *((const uint4*)(Mu + (size_t)d0 * NH) + q);
                add8(acc, v0);
            }
            #pragma unroll
            for (int k = 0; k < 8; ++k) {
                acc[k] += __shfl_xor(acc[k], 16, 64);
                acc[k] += __shfl_xor(acc[k], 32, 64);
            }
            if (l < 16 && n < N) {
                float4 bA0 = *(const float4*)&bA[q * 8];
                float4 bA1 = *(const float4*)&bA[q * 8 + 4];
                float4 o0 = make_float4(0.5f * (acc[0] + bA0.x), 0.5f * (acc[1] + bA0.y),
                                        0.5f * (acc[2] + bA0.z), 0.5f * (acc[3] + bA0.w));
                float4 o1 = make_float4(0.5f * (acc[4] + bA1.x), 0.5f * (acc[5] + bA1.y),
                                        0.5f * (acc[6] + bA1.z), 0.5f * (acc[7] + bA1.w));
                *(float4*)&axbuf2[(size_t)n * NH + q * 8]     = o0;
                *(float4*)&axbuf2[(size_t)n * NH + q * 8 + 4] = o1;
            }
        }
        return;
    }

    // ---------------- path (round-9 structure; block index = idx) ----------
    bf16*  path_s = (bf16*)smem;                 // [2][32*256]  32768 B
    bf16*  h_sb   = (bf16*)(smem + 32768);       // [2][4][128]   2048 B
    float* s_red  = (float*)(smem + 34816);      // [4][32]        512 B

    const int w   = tid >> 6;
    const int l   = tid & 63;
    const int c   = l & 15;
    const int g   = l >> 4;
    const int nl  = g >> 1;            // local node (within a pair)

    bf16x8 bfrag[2][8];
    #pragma unroll
    for (int ht = 0; ht < 2; ++ht) {
        int hg = (w * 2 + ht) * 16 + c;
        #pragma unroll
        for (int ks = 0; ks < 8; ++ks) {
            const float* src = &Wpath[(size_t)hg * 256 + ks * 32 + g * 8];
            bfrag[ht][ks] = cvt8(*(const float4*)src, *(const float4*)(src + 4));
        }
    }
    const float bp0 = bpath[(w * 2 + 0) * 16 + c];
    const float bp1 = bpath[(w * 2 + 1) * 16 + c];

    auto stage = [&](int round, int b) {
        const int n0 = round * 4;
        #pragma unroll
        for (int rr = 0; rr < 4; ++rr) {
            int id  = rr * 256 + tid;
            int row = id >> 5;
            int cc  = id & 31;
            int ls  = cc ^ (row & 7);      // source-side swizzle
            int d   = ls >> 3, q = ls & 7;
            int nn  = row >> 3, p = row & 7;
            int idx2 = index[(size_t)(n0 + nn) * (NP * ND) + p * ND + d];
            GLOAD_LDS16(pp + (size_t)idx2 * NPH + q * 8, &path_s[b * 8192 + id * 8]);
        }
        if (tid < 64) {
            int node = tid >> 4, q = tid & 15;   // 4 nodes x 16 chunks of 8 bf16
            GLOAD_LDS16(hb + (size_t)(n0 + node) * NH + q * 8,
                        &h_sb[(b * 4 + node) * 128 + q * 8]);
        }
    };

    int r = idx;
    const int G = gridDim.x - nbuck;  // NPATH
    if (r < nrounds) stage(r, 0);
    int buf = 0;

    for (; r < nrounds; r += G) {
        const int n0 = r * 4;
        __syncthreads();                        // round-r stage complete
        if (r + G < nrounds) stage(r + G, buf ^ 1);   // prefetch next round

        f32x4 acc[2][2] = {};
        #pragma unroll
        for (int rt = 0; rt < 2; ++rt) {
            const int rowbase = buf * 8192 + (rt * 16 + c) * 256;
            #pragma unroll
            for (int ks = 0; ks < 8; ++ks) {
                int chunk = (ks * 4 + g) ^ (c & 7);     // read-side XOR
                bf16x8 a = *(const bf16x8*)&path_s[rowbase + chunk * 8];
                acc[rt][0] = __builtin_amdgcn_mfma_f32_16x16x32_bf16(
                    a, bfrag[0][ks], acc[rt][0], 0, 0, 0);
                acc[rt][1] = __builtin_amdgcn_mfma_f32_16x16x32_bf16(
                    a, bfrag[1][ks], acc[rt][1], 0, 0, 0);
            }
        }

        float pi[2][2][4];
        #pragma unroll
        for (int rt = 0; rt < 2; ++rt) {
            const float hv0 = (float)h_sb[(buf * 4 + rt * 2 + nl) * 128 + w * 32 + c];
            const float hv1 = (float)h_sb[(buf * 4 + rt * 2 + nl) * 128 + w * 32 + 16 + c];
            float sp[4];
            #pragma unroll
            for (int i = 0; i < 4; ++i) {
                pi[rt][0][i] = gelu_fast(acc[rt][0][i] + bp0);
                pi[rt][1][i] = gelu_fast(acc[rt][1][i] + bp1);
                sp[i] = hv0 * pi[rt][0][i] + hv1 * pi[rt][1][i];
            }
            #pragma unroll
            for (int i = 0; i < 4; ++i) sp[i] = row16_sum(sp[i]);
            float v = (c == 0) ? sp[0] : (c == 1) ? sp[1] : (c == 2) ? sp[2] : sp[3];
            if (c < 4) s_red[w * 32 + rt * 16 + g * 4 + c] = v;
        }

        __builtin_amdgcn_sched_barrier(0);
        asm volatile("s_waitcnt lgkmcnt(0)" ::: "memory");
        __builtin_amdgcn_s_barrier();
        __builtin_amdgcn_sched_barrier(0);

        #pragma unroll
        for (int rt = 0; rt < 2; ++rt) {
            float4 r0 = *(const float4*)&s_red[0 * 32 + rt * 16 + g * 4];
            float4 r1 = *(const float4*)&s_red[1 * 32 + rt * 16 + g * 4];
            float4 r2 = *(const float4*)&s_red[2 * 32 + rt * 16 + g * 4];
            float4 r3 = *(const float4*)&s_red[3 * 32 + rt * 16 + g * 4];
            float st[4];
            st[0] = r0.x + r1.x + r2.x + r3.x;
            st[1] = r0.y + r1.y + r2.y + r3.y;
            st[2] = r0.z + r1.z + r2.z + r3.z;
            st[3] = r0.w + r1.w + r2.w + r3.w;
            float m4 = fmaxf(fmaxf(st[0], st[1]), fmaxf(st[2], st[3]));
            float m  = fmaxf(m4, __shfl_xor(m4, 16, 64));
            float e[4], s4 = 0.f;
            #pragma unroll
            for (int i = 0; i < 4; ++i) { e[i] = __expf(st[i] - m); s4 += e[i]; }
            float den = s4 + __shfl_xor(s4, 16, 64);
            const float inv = __builtin_amdgcn_rcpf(den);

            float pa0 = 0.f, pa1 = 0.f;
            #pragma unroll
            for (int i = 0; i < 4; ++i) {
                pa0 += e[i] * pi[rt][0][i];
                pa1 += e[i] * pi[rt][1][i];
            }
            pa0 = (pa0 + __shfl_xor(pa0, 16, 64)) * inv;
            pa1 = (pa1 + __shfl_xor(pa1, 16, 64)) * inv;

            if (!(g & 1)) {
                int n = n0 + rt * 2 + nl;
                const float hv0 = (float)h_sb[(buf * 4 + rt * 2 + nl) * 128 + w * 32 + c];
                const float hv1 = (float)h_sb[(buf * 4 + rt * 2 + nl) * 128 + w * 32 + 16 + c];
                aggbuf[(size_t)n * NH + w * 32 + c]      = 0.5f * (pa0 + hv0);
                aggbuf[(size_t)n * NH + w * 32 + 16 + c] = 0.5f * (pa1 + hv1);
            }
        }
        buf ^= 1;
    }
}

// ---------------------------------------------------------------------------
// k_fin: out = gelu(aggbuf + axbuf2) @ Wend.T + bend  (memory-bound, ~51 MB)
// ---------------------------------------------------------------------------
__global__ __launch_bounds__(256) void k_fin(
    const float* __restrict__ aggbuf, const float* __restrict__ axbuf2,
    const float* __restrict__ Wend, const float* __restrict__ bend,
    float* __restrict__ out, int N)
{
    __shared__ float wend_s[NC][128];
    __shared__ float bend_s[NC];
    const int tid = threadIdx.x;
    for (int id = tid; id < NC * 128; id += 256) wend_s[id >> 7][id & 127] = Wend[id];
    if (tid < NC) bend_s[tid] = bend[tid];
    __syncthreads();

    const int w = tid >> 6, l = tid & 63;
    const int n = blockIdx.x * 4 + w;
    if (n >= N) return;
    const int q = l & 15;

    float4 agA = *(const float4*)&aggbuf[(size_t)n * NH + q * 8];
    float4 agB = *(const float4*)&aggbuf[(size_t)n * NH + q * 8 + 4];
    float4 axA = *(const float4*)&axbuf2[(size_t)n * NH + q * 8];
    float4 axB = *(const float4*)&axbuf2[(size_t)n * NH + q * 8 + 4];
    float gg[8];
    gg[0] = gelu_fast(agA.x + axA.x);
    gg[1] = gelu_fast(agA.y + axA.y);
    gg[2] = gelu_fast(agA.z + axA.z);
    gg[3] = gelu_fast(agA.w + axA.w);
    gg[4] = gelu_fast(agB.x + axB.x);
    gg[5] = gelu_fast(agB.y + axB.y);
    gg[6] = gelu_fast(agB.z + axB.z);
    gg[7] = gelu_fast(agB.w + axB.w);

    float part[NC];
    #pragma unroll
    for (int cc = 0; cc < NC; ++cc) {
        float p = 0.f;
        #pragma unroll
        for (int k = 0; k < 8; ++k) p += gg[k] * wend_s[cc][q * 8 + k];
        part[cc] = row16_sum(p);
    }

    float r = part[0];
    #pragma unroll
    for (int cc = 1; cc < NC; ++cc) r = (l == cc) ? part[cc] : r;
    if (l < NC) out[(size_t)n * NC + l] = r + bend_s[l];
}

// ---------------------------------------------------------------------------
extern "C" void kernel_launch(void* const* d_in, const int* in_sizes, int n_in,
                              void* d_out, int out_size, void* d_ws, size_t ws_size,
                              hipStream_t stream)
{
    const float* x     = (const float*)d_in[0];
    const float* Wproj = (const float*)d_in[1];
    const float* bproj = (const float*)d_in[2];
    const float* Wx    = (const float*)d_in[3];
    const float* bx    = (const float*)d_in[4];
    const float* Wpath = (const float*)d_in[5];
    const float* bpath = (const float*)d_in[6];
    const float* WA    = (const float*)d_in[7];
    const float* bA    = (const float*)d_in[8];
    const float* Wend  = (const float*)d_in[9];
    const float* bend  = (const float*)d_in[10];
    const int*   index = (const int*)d_in[11];
    const int*   eidx  = (const int*)d_in[12];

    const int N = in_sizes[0] / NF;
    const int E = in_sizes[12] / 2;
    const int* esrc = eidx;
    const int* edst = eidx + E;
    const int nbuck = (N + 63) >> 6;     // 64-node buckets (needs N <= 65536)

    char* p = (char*)d_ws;
    auto alloc = [&](size_t bytes) {
        char* r = p;
        p += (bytes + 255) & ~(size_t)255;
        return r;
    };
    bf16*     pp     = (bf16*)alloc((size_t)N * NPH * sizeof(bf16));
    bf16*     hb     = (bf16*)alloc((size_t)N * NH * sizeof(bf16));
    float*    aggbuf = (float*)alloc((size_t)N * NH * sizeof(float));
    float*    axbuf2 = (float*)alloc((size_t)N * NH * sizeof(float));
    bf16*     Mb     = (bf16*)alloc((size_t)N * NH * sizeof(bf16));
    unsigned* pairs  = (unsigned*)alloc((size_t)nbuck * BCAP * sizeof(unsigned));
    int*      gcur   = (int*)alloc((size_t)nbuck * sizeof(int));

    const int nbP = (N + 63) / 64;
    const int nbT = (N + 63) / 64;
    const int nbB = (E + 4095) / 4096;
    const int NPATH = 1024;
    const int nrounds = N / 4;

    hipMemsetAsync(gcur, 0, (size_t)nbuck * sizeof(int), stream);
    k_front<<<nbP + nbT + nbB, 256, 0, stream>>>(
        x, Wproj, bproj, Wx, bx, pp, hb, WA, Mb, esrc, edst, gcur, pairs,
        N, E, nbuck, nbP, nbT);
    k_mid2<<<nbuck + NPATH, 256, 0, stream>>>(
        pairs, gcur, Mb, bA, axbuf2, pp, hb, Wpath, bpath, index, aggbuf,
        N, E, nbuck, nrounds);
    k_fin<<<(N + 3) / 4, 256, 0, stream>>>(aggbuf, axbuf2, Wend, bend,
                                           (float*)d_out, N);
}

// Round 17
// 232.015 us; speedup vs baseline: 1.1785x; 1.0002x over previous
//
#include <hip/hip_runtime.h>
#include <hip/hip_bf16.h>
#include <math.h>

#define NF   128   // F
#define NPH  64    // PH
#define NP   8     // P
#define ND   4     // D
#define NH   128   // H
#define NC   10    // C
#define BCAP 2560  // 64-node bucket capacity (mean ~2046, 11 sigma slack)

typedef __bf16 bf16;
typedef __attribute__((ext_vector_type(4))) __bf16 bf16x4;
typedef __attribute__((ext_vector_type(8))) __bf16 bf16x8;
typedef __attribute__((ext_vector_type(4))) float f32x4;

// DPP rotate-reduce within each 16-lane row: pure VALU, no LDS.
template<int CTRL>
__device__ __forceinline__ float dpp_add(float x) {
    int t = __builtin_amdgcn_update_dpp(0, __float_as_int(x), CTRL, 0xf, 0xf, false);
    return x + __int_as_float(t);
}
__device__ __forceinline__ float row16_sum(float x) {
    x = dpp_add<0x121>(x);   // row_ror:1
    x = dpp_add<0x122>(x);   // row_ror:2
    x = dpp_add<0x124>(x);   // row_ror:4
    x = dpp_add<0x128>(x);   // row_ror:8
    return x;
}

// fast exact-erf GELU: Abramowitz-Stegun 7.1.25 (3-term), |eps|<=2.5e-5
__device__ __forceinline__ float gelu_fast(float x) {
    float z = fabsf(x) * 0.70710678118654752f;
    float t = __builtin_amdgcn_rcpf(1.0f + 0.47047f * z);
    float poly = t * (0.3480242f + t * (-0.0958798f + t * 0.7478556f));
    float erfv = 1.0f - poly * __expf(-z * z);
    float s = copysignf(erfv, x);
    return 0.5f * x * (1.0f + s);
}

#define GLOAD_LDS16(g, l)                                                     \
    __builtin_amdgcn_global_load_lds(                                         \
        (const __attribute__((address_space(1))) unsigned int*)(g),           \
        (__attribute__((address_space(3))) unsigned int*)(l), 16, 0, 0)

__device__ __forceinline__ bf16x8 cvt8(float4 a, float4 b) {
    bf16x8 r;
    r[0] = (bf16)a.x; r[1] = (bf16)a.y; r[2] = (bf16)a.z; r[3] = (bf16)a.w;
    r[4] = (bf16)b.x; r[5] = (bf16)b.y; r[6] = (bf16)b.z; r[7] = (bf16)b.w;
    return r;
}

__device__ __forceinline__ void add8(float* a, uint4 v) {
    a[0] += __uint_as_float(v.x << 16);  a[1] += __uint_as_float(v.x & 0xffff0000u);
    a[2] += __uint_as_float(v.y << 16);  a[3] += __uint_as_float(v.y & 0xffff0000u);
    a[4] += __uint_as_float(v.z << 16);  a[5] += __uint_as_float(v.z & 0xffff0000u);
    a[6] += __uint_as_float(v.w << 16);  a[7] += __uint_as_float(v.w & 0xffff0000u);
}

// ---------------------------------------------------------------------------
// k_front: fused [proj | transpose | bucket], parity-interleaved classes.
// ---------------------------------------------------------------------------
__global__ __launch_bounds__(256) void k_front(
    const float* __restrict__ x,
    const float* __restrict__ Wproj, const float* __restrict__ bproj,
    const float* __restrict__ Wx,    const float* __restrict__ bx,
    bf16* __restrict__ pp, bf16* __restrict__ hb,
    const float* __restrict__ WA, bf16* __restrict__ Mb,
    const int* __restrict__ esrc, const int* __restrict__ edst,
    int* __restrict__ gcur, unsigned* __restrict__ pairs,
    int N, int E, int nbuck, int nbP, int nbT)
{
    __shared__ alignas(16) char smem[33280];
    const int tid = threadIdx.x;

    const int bid = blockIdx.x;
    const int two = 2 * nbP;
    int cls, idx;
    if (bid < two) { cls = bid & 1; idx = bid >> 1; }
    else           { cls = 1; idx = nbP + (bid - two); }

    if (cls == 0) {
        // ---------------- proj ----------------
        bf16* x_s = (bf16*)smem;                 // [64][136]
        const int w = tid >> 6, l = tid & 63;
        const int c = l & 15, g = l >> 4;

        bf16x8 bfr[3][4];
        float bias[3];
        #pragma unroll
        for (int t = 0; t < 3; ++t) {
            int ch = (w * 3 + t) * 16 + c;
            const float* wr = (ch < NPH) ? &Wproj[(size_t)ch * NF]
                                         : &Wx[(size_t)(ch - NPH) * NF];
            bias[t] = (ch < NPH) ? bproj[ch] : bx[ch - NPH];
            #pragma unroll
            for (int ks = 0; ks < 4; ++ks) {
                const float* src = wr + ks * 32 + g * 8;
                bfr[t][ks] = cvt8(*(const float4*)src, *(const float4*)(src + 4));
            }
        }

        const int n0 = idx * 64;
        #pragma unroll
        for (int rr = 0; rr < 8; ++rr) {
            int id  = rr * 256 + tid;
            int row = id >> 5, c4 = id & 31;
            float4 v = make_float4(0.f, 0.f, 0.f, 0.f);
            if (n0 + row < N) v = *(const float4*)&x[(size_t)(n0 + row) * NF + c4 * 4];
            bf16x4 o;
            o[0] = (bf16)v.x; o[1] = (bf16)v.y; o[2] = (bf16)v.z; o[3] = (bf16)v.w;
            *(bf16x4*)&x_s[row * 136 + c4 * 4] = o;
        }
        __syncthreads();

        f32x4 acc[4][3] = {};
        #pragma unroll
        for (int rt = 0; rt < 4; ++rt)
            #pragma unroll
            for (int ks = 0; ks < 4; ++ks) {
                bf16x8 a = *(const bf16x8*)&x_s[(rt * 16 + c) * 136 + ks * 32 + g * 8];
                #pragma unroll
                for (int t = 0; t < 3; ++t)
                    acc[rt][t] = __builtin_amdgcn_mfma_f32_16x16x32_bf16(
                        a, bfr[t][ks], acc[rt][t], 0, 0, 0);
            }

        #pragma unroll
        for (int rt = 0; rt < 4; ++rt) {
            #pragma unroll
            for (int t = 0; t < 3; ++t) {
                int ch = (w * 3 + t) * 16 + c;
                #pragma unroll
                for (int i = 0; i < 4; ++i) {
                    int n = n0 + rt * 16 + g * 4 + i;
                    if (n >= N) continue;
                    float v = acc[rt][t][i] + bias[t];
                    if (ch < NPH) pp[(size_t)n * NPH + ch] = (bf16)v;
                    else          hb[(size_t)n * NH + (ch - NPH)] = (bf16)gelu_fast(v);
                }
            }
        }
    } else if (idx < nbT) {
        // ---------------- transpose ----------------
        float* tt = (float*)smem;                // [128][65]
        const int n0 = idx * 64;
        const int w = tid >> 6, l = tid & 63;
        #pragma unroll
        for (int rep = 0; rep < 32; ++rep) {
            int hh = rep * 4 + w;
            int n  = n0 + l;
            tt[hh * 65 + l] = (n < N) ? WA[(size_t)hh * N + n] : 0.f;
        }
        __syncthreads();
        #pragma unroll
        for (int rep = 0; rep < 32; ++rep) {
            int n_l = rep * 2 + (tid >> 7);
            int n   = n0 + n_l;
            if (n < N) Mb[(size_t)n * NH + (tid & 127)] = (bf16)tt[(tid & 127) * 65 + n_l];
        }
    } else {
        // ---------------- bucket (2-pass, tile 4096 edges) ----------------
        int* cnt  = (int*)smem;          // [<=800]
        int* bofs = cnt + 800;
        const int tile = (idx - nbT) * 4096;
        for (int i = tid; i < nbuck; i += 256) cnt[i] = 0;
        __syncthreads();
        #pragma unroll
        for (int k = 0; k < 16; ++k) {
            int i = tile + k * 256 + tid;
            if (i < E) atomicAdd(&cnt[esrc[i] >> 6], 1);
        }
        __syncthreads();
        for (int i = tid; i < nbuck; i += 256) {
            int c = cnt[i];
            bofs[i] = c ? atomicAdd(&gcur[i], c) : 0;
            cnt[i] = 0;
        }
        __syncthreads();
        #pragma unroll
        for (int k = 0; k < 16; ++k) {
            int i = tile + k * 256 + tid;
            if (i < E) {
                int s = esrc[i], b = s >> 6;
                int r = atomicAdd(&cnt[b], 1);
                pairs[(size_t)b * BCAP + bofs[b] + r] =
                    ((unsigned)(s & 63) << 16) | (unsigned)edst[i];
            }
        }
    }
}

// ---------------------------------------------------------------------------
// k_mid2: fused [ax | path], parity-interleaved, launch_bounds(256,3).
// aggbuf/axbuf2 stored bf16 (write traffic halved; intermediates only).
// ---------------------------------------------------------------------------
__global__ __launch_bounds__(256, 3) void k_mid2(
    const unsigned* __restrict__ pairs, const int* __restrict__ gcur,
    const bf16* __restrict__ Mb, const float* __restrict__ bA,
    bf16* __restrict__ axbuf2,
    const bf16* __restrict__ pp, const bf16* __restrict__ hb,
    const float* __restrict__ Wpath, const float* __restrict__ bpath,
    const int* __restrict__ index, bf16* __restrict__ aggbuf,
    int N, int E, int nbuck, int nrounds)
{
    __shared__ alignas(16) char smem[35328];
    const int tid = threadIdx.x;

    // interleave: bid<2*nbuck: odd->ax, even->path; tail->path
    const int bid = blockIdx.x;
    const int two = 2 * nbuck;
    int cls, idx;
    if (bid < two) { cls = bid & 1; idx = bid >> 1; }
    else           { cls = 0; idx = nbuck + (bid - two); }

    if (cls == 1) {
        // ---------------- ax: in-LDS sort + gather (bucket idx) ----------------
        int* hist  = (int*)smem;                       // [64]
        int* sc    = hist + 64;                        // [64] inclusive scan
        int* cur   = hist + 128;                       // [64]
        unsigned short* dstl = (unsigned short*)(smem + 768);  // [BCAP]
        const int b = idx, t = tid;
        const int cnt = gcur[b];
        const unsigned* pb = pairs + (size_t)b * BCAP;

        if (t < 64) hist[t] = 0;
        __syncthreads();
        for (int j = t; j < cnt; j += 256)
            atomicAdd(&hist[pb[j] >> 16], 1);
        __syncthreads();
        if (t < 64) sc[t] = hist[t];
        __syncthreads();
        for (int off = 1; off < 64; off <<= 1) {
            int u = (t < 64 && t >= off) ? sc[t - off] : 0;
            __syncthreads();
            if (t < 64) sc[t] += u;
            __syncthreads();
        }
        if (t < 64) cur[t] = sc[t] - hist[t];          // exclusive base
        __syncthreads();
        for (int j = t; j < cnt; j += 256) {
            unsigned p = pb[j];
            int pos = atomicAdd(&cur[p >> 16], 1);
            dstl[pos] = (unsigned short)(p & 0xffffu);
        }
        __syncthreads();

        // gather: wave w handles nodes w, w+4, ... (16 per wave)
        const int w = t >> 6, l = t & 63;
        const int e = l >> 4, q = l & 15;
        const unsigned short* Mu = (const unsigned short*)Mb;
        const int nb0 = b * 64;
        #pragma unroll 1
        for (int it = 0; it < 16; ++it) {
            const int node = it * 4 + w;
            const int n = nb0 + node;
            const int le = sc[node];
            int j = le - hist[node];
            float acc[8] = {0.f, 0.f, 0.f, 0.f, 0.f, 0.f, 0.f, 0.f};
            for (; j + 32 <= le; j += 32) {
                int d[8];
                #pragma unroll
                for (int k = 0; k < 8; ++k) d[k] = dstl[j + k * 4 + e];
                uint4 v[8];
                #pragma unroll
                for (int k = 0; k < 8; ++k)
                    v[k] = *((const uint4*)(Mu + (size_t)d[k] * NH) + q);
                #pragma unroll
                for (int k = 0; k < 8; ++k) add8(acc, v[k]);
            }
            for (; j + 4 <= le; j += 4) {
                int d0 = dstl[j + e];
                uint4 v0 = *((const uint4*)(Mu + (size_t)d0 * NH) + q);
                add8(acc, v0);
            }
            if (e < le - j) {
                int d0 = dstl[j + e];
                uint4 v0 = *((const uint4*)(Mu + (size_t)d0 * NH) + q);
                add8(acc, v0);
            }
            #pragma unroll
            for (int k = 0; k < 8; ++k) {
                acc[k] += __shfl_xor(acc[k], 16, 64);
                acc[k] += __shfl_xor(acc[k], 32, 64);
            }
            if (l < 16 && n < N) {
                float4 bA0 = *(const float4*)&bA[q * 8];
                float4 bA1 = *(const float4*)&bA[q * 8 + 4];
                bf16x8 o;
                o[0] = (bf16)(0.5f * (acc[0] + bA0.x));
                o[1] = (bf16)(0.5f * (acc[1] + bA0.y));
                o[2] = (bf16)(0.5f * (acc[2] + bA0.z));
                o[3] = (bf16)(0.5f * (acc[3] + bA0.w));
                o[4] = (bf16)(0.5f * (acc[4] + bA1.x));
                o[5] = (bf16)(0.5f * (acc[5] + bA1.y));
                o[6] = (bf16)(0.5f * (acc[6] + bA1.z));
                o[7] = (bf16)(0.5f * (acc[7] + bA1.w));
                *(bf16x8*)&axbuf2[(size_t)n * NH + q * 8] = o;
            }
        }
        return;
    }

    // ---------------- path (round-9 structure; block index = idx) ----------
    bf16*  path_s = (bf16*)smem;                 // [2][32*256]  32768 B
    bf16*  h_sb   = (bf16*)(smem + 32768);       // [2][4][128]   2048 B
    float* s_red  = (float*)(smem + 34816);      // [4][32]        512 B

    const int w   = tid >> 6;
    const int l   = tid & 63;
    const int c   = l & 15;
    const int g   = l >> 4;
    const int nl  = g >> 1;            // local node (within a pair)

    bf16x8 bfrag[2][8];
    #pragma unroll
    for (int ht = 0; ht < 2; ++ht) {
        int hg = (w * 2 + ht) * 16 + c;
        #pragma unroll
        for (int ks = 0; ks < 8; ++ks) {
            const float* src = &Wpath[(size_t)hg * 256 + ks * 32 + g * 8];
            bfrag[ht][ks] = cvt8(*(const float4*)src, *(const float4*)(src + 4));
        }
    }
    const float bp0 = bpath[(w * 2 + 0) * 16 + c];
    const float bp1 = bpath[(w * 2 + 1) * 16 + c];

    auto stage = [&](int round, int b) {
        const int n0 = round * 4;
        #pragma unroll
        for (int rr = 0; rr < 4; ++rr) {
            int id  = rr * 256 + tid;
            int row = id >> 5;
            int cc  = id & 31;
            int ls  = cc ^ (row & 7);      // source-side swizzle
            int d   = ls >> 3, q = ls & 7;
            int nn  = row >> 3, p = row & 7;
            int idx2 = index[(size_t)(n0 + nn) * (NP * ND) + p * ND + d];
            GLOAD_LDS16(pp + (size_t)idx2 * NPH + q * 8, &path_s[b * 8192 + id * 8]);
        }
        if (tid < 64) {
            int node = tid >> 4, q = tid & 15;   // 4 nodes x 16 chunks of 8 bf16
            GLOAD_LDS16(hb + (size_t)(n0 + node) * NH + q * 8,
                        &h_sb[(b * 4 + node) * 128 + q * 8]);
        }
    };

    int r = idx;
    const int G = gridDim.x - nbuck;  // NPATH
    if (r < nrounds) stage(r, 0);
    int buf = 0;

    for (; r < nrounds; r += G) {
        const int n0 = r * 4;
        __syncthreads();                        // round-r stage complete
        if (r + G < nrounds) stage(r + G, buf ^ 1);   // prefetch next round

        f32x4 acc[2][2] = {};
        #pragma unroll
        for (int rt = 0; rt < 2; ++rt) {
            const int rowbase = buf * 8192 + (rt * 16 + c) * 256;
            #pragma unroll
            for (int ks = 0; ks < 8; ++ks) {
                int chunk = (ks * 4 + g) ^ (c & 7);     // read-side XOR
                bf16x8 a = *(const bf16x8*)&path_s[rowbase + chunk * 8];
                acc[rt][0] = __builtin_amdgcn_mfma_f32_16x16x32_bf16(
                    a, bfrag[0][ks], acc[rt][0], 0, 0, 0);
                acc[rt][1] = __builtin_amdgcn_mfma_f32_16x16x32_bf16(
                    a, bfrag[1][ks], acc[rt][1], 0, 0, 0);
            }
        }

        float pi[2][2][4];
        #pragma unroll
        for (int rt = 0; rt < 2; ++rt) {
            const float hv0 = (float)h_sb[(buf * 4 + rt * 2 + nl) * 128 + w * 32 + c];
            const float hv1 = (float)h_sb[(buf * 4 + rt * 2 + nl) * 128 + w * 32 + 16 + c];
            float sp[4];
            #pragma unroll
            for (int i = 0; i < 4; ++i) {
                pi[rt][0][i] = gelu_fast(acc[rt][0][i] + bp0);
                pi[rt][1][i] = gelu_fast(acc[rt][1][i] + bp1);
                sp[i] = hv0 * pi[rt][0][i] + hv1 * pi[rt][1][i];
            }
            #pragma unroll
            for (int i = 0; i < 4; ++i) sp[i] = row16_sum(sp[i]);
            float v = (c == 0) ? sp[0] : (c == 1) ? sp[1] : (c == 2) ? sp[2] : sp[3];
            if (c < 4) s_red[w * 32 + rt * 16 + g * 4 + c] = v;
        }

        __builtin_amdgcn_sched_barrier(0);
        asm volatile("s_waitcnt lgkmcnt(0)" ::: "memory");
        __builtin_amdgcn_s_barrier();
        __builtin_amdgcn_sched_barrier(0);

        #pragma unroll
        for (int rt = 0; rt < 2; ++rt) {
            float4 r0 = *(const float4*)&s_red[0 * 32 + rt * 16 + g * 4];
            float4 r1 = *(const float4*)&s_red[1 * 32 + rt * 16 + g * 4];
            float4 r2 = *(const float4*)&s_red[2 * 32 + rt * 16 + g * 4];
            float4 r3 = *(const float4*)&s_red[3 * 32 + rt * 16 + g * 4];
            float st[4];
            st[0] = r0.x + r1.x + r2.x + r3.x;
            st[1] = r0.y + r1.y + r2.y + r3.y;
            st[2] = r0.z + r1.z + r2.z + r3.z;
            st[3] = r0.w + r1.w + r2.w + r3.w;
            float m4 = fmaxf(fmaxf(st[0], st[1]), fmaxf(st[2], st[3]));
            float m  = fmaxf(m4, __shfl_xor(m4, 16, 64));
            float e[4], s4 = 0.f;
            #pragma unroll
            for (int i = 0; i < 4; ++i) { e[i] = __expf(st[i] - m); s4 += e[i]; }
            float den = s4 + __shfl_xor(s4, 16, 64);
            const float inv = __builtin_amdgcn_rcpf(den);

            float pa0 = 0.f, pa1 = 0.f;
            #pragma unroll
            for (int i = 0; i < 4; ++i) {
                pa0 += e[i] * pi[rt][0][i];
                pa1 += e[i] * pi[rt][1][i];
            }
            pa0 = (pa0 + __shfl_xor(pa0, 16, 64)) * inv;
            pa1 = (pa1 + __shfl_xor(pa1, 16, 64)) * inv;

            if (!(g & 1)) {
                int n = n0 + rt * 2 + nl;
                const float hv0 = (float)h_sb[(buf * 4 + rt * 2 + nl) * 128 + w * 32 + c];
                const float hv1 = (float)h_sb[(buf * 4 + rt * 2 + nl) * 128 + w * 32 + 16 + c];
                aggbuf[(size_t)n * NH + w * 32 + c]      = (bf16)(0.5f * (pa0 + hv0));
                aggbuf[(size_t)n * NH + w * 32 + 16 + c] = (bf16)(0.5f * (pa1 + hv1));
            }
        }
        buf ^= 1;
    }
}

// ---------------------------------------------------------------------------
// k_fin: out = gelu(aggbuf + axbuf2) @ Wend.T + bend  (bf16 in, ~32 MB total)
// ---------------------------------------------------------------------------
__global__ __launch_bounds__(256) void k_fin(
    const bf16* __restrict__ aggbuf, const bf16* __restrict__ axbuf2,
    const float* __restrict__ Wend, const float* __restrict__ bend,
    float* __restrict__ out, int N)
{
    __shared__ float wend_s[NC][128];
    __shared__ float bend_s[NC];
    const int tid = threadIdx.x;
    for (int id = tid; id < NC * 128; id += 256) wend_s[id >> 7][id & 127] = Wend[id];
    if (tid < NC) bend_s[tid] = bend[tid];
    __syncthreads();

    const int w = tid >> 6, l = tid & 63;
    const int n = blockIdx.x * 4 + w;
    if (n >= N) return;
    const int q = l & 15;

    bf16x8 ag = *(const bf16x8*)&aggbuf[(size_t)n * NH + q * 8];
    bf16x8 ax = *(const bf16x8*)&axbuf2[(size_t)n * NH + q * 8];
    float gg[8];
    #pragma unroll
    for (int k = 0; k < 8; ++k)
        gg[k] = gelu_fast((float)ag[k] + (float)ax[k]);

    float part[NC];
    #pragma unroll
    for (int cc = 0; cc < NC; ++cc) {
        float p = 0.f;
        #pragma unroll
        for (int k = 0; k < 8; ++k) p += gg[k] * wend_s[cc][q * 8 + k];
        part[cc] = row16_sum(p);
    }

    float r = part[0];
    #pragma unroll
    for (int cc = 1; cc < NC; ++cc) r = (l == cc) ? part[cc] : r;
    if (l < NC) out[(size_t)n * NC + l] = r + bend_s[l];
}

// ---------------------------------------------------------------------------
extern "C" void kernel_launch(void* const* d_in, const int* in_sizes, int n_in,
                              void* d_out, int out_size, void* d_ws, size_t ws_size,
                              hipStream_t stream)
{
    const float* x     = (const float*)d_in[0];
    const float* Wproj = (const float*)d_in[1];
    const float* bproj = (const float*)d_in[2];
    const float* Wx    = (const float*)d_in[3];
    const float* bx    = (const float*)d_in[4];
    const float* Wpath = (const float*)d_in[5];
    const float* bpath = (const float*)d_in[6];
    const float* WA    = (const float*)d_in[7];
    const float* bA    = (const float*)d_in[8];
    const float* Wend  = (const float*)d_in[9];
    const float* bend  = (const float*)d_in[10];
    const int*   index = (const int*)d_in[11];
    const int*   eidx  = (const int*)d_in[12];

    const int N = in_sizes[0] / NF;
    const int E = in_sizes[12] / 2;
    const int* esrc = eidx;
    const int* edst = eidx + E;
    const int nbuck = (N + 63) >> 6;     // 64-node buckets (needs N <= 65536)

    char* p = (char*)d_ws;
    auto alloc = [&](size_t bytes) {
        char* r = p;
        p += (bytes + 255) & ~(size_t)255;
        return r;
    };
    bf16*     pp     = (bf16*)alloc((size_t)N * NPH * sizeof(bf16));
    bf16*     hb     = (bf16*)alloc((size_t)N * NH * sizeof(bf16));
    bf16*     aggbuf = (bf16*)alloc((size_t)N * NH * sizeof(bf16));
    bf16*     axbuf2 = (bf16*)alloc((size_t)N * NH * sizeof(bf16));
    bf16*     Mb     = (bf16*)alloc((size_t)N * NH * sizeof(bf16));
    unsigned* pairs  = (unsigned*)alloc((size_t)nbuck * BCAP * sizeof(unsigned));
    int*      gcur   = (int*)alloc((size_t)nbuck * sizeof(int));

    const int nbP = (N + 63) / 64;
    const int nbT = (N + 63) / 64;
    const int nbB = (E + 4095) / 4096;
    const int NPATH = 1024;
    const int nrounds = N / 4;

    hipMemsetAsync(gcur, 0, (size_t)nbuck * sizeof(int), stream);
    k_front<<<nbP + nbT + nbB, 256, 0, stream>>>(
        x, Wproj, bproj, Wx, bx, pp, hb, WA, Mb, esrc, edst, gcur, pairs,
        N, E, nbuck, nbP, nbT);
    k_mid2<<<nbuck + NPATH, 256, 0, stream>>>(
        pairs, gcur, Mb, bA, axbuf2, pp, hb, Wpath, bpath, index, aggbuf,
        N, E, nbuck, nrounds);
    k_fin<<<(N + 3) / 4, 256, 0, stream>>>(aggbuf, axbuf2, Wend, bend,
                                           (float*)d_out, N);
}

// Round 18
// 230.259 us; speedup vs baseline: 1.1875x; 1.0076x over previous
//
#include <hip/hip_runtime.h>
#include <hip/hip_bf16.h>
#include <math.h>

#define NF   128   // F
#define NPH  64    // PH
#define NP   8     // P
#define ND   4     // D
#define NH   128   // H
#define NC   10    // C
#define BCAP 2560  // 64-node bucket capacity (mean ~2046, 11 sigma slack)

typedef __bf16 bf16;
typedef __attribute__((ext_vector_type(4))) __bf16 bf16x4;
typedef __attribute__((ext_vector_type(8))) __bf16 bf16x8;
typedef __attribute__((ext_vector_type(4))) float f32x4;

// DPP rotate-reduce within each 16-lane row: pure VALU, no LDS.
template<int CTRL>
__device__ __forceinline__ float dpp_add(float x) {
    int t = __builtin_amdgcn_update_dpp(0, __float_as_int(x), CTRL, 0xf, 0xf, false);
    return x + __int_as_float(t);
}
__device__ __forceinline__ float row16_sum(float x) {
    x = dpp_add<0x121>(x);   // row_ror:1
    x = dpp_add<0x122>(x);   // row_ror:2
    x = dpp_add<0x124>(x);   // row_ror:4
    x = dpp_add<0x128>(x);   // row_ror:8
    return x;
}

// fast exact-erf GELU: Abramowitz-Stegun 7.1.25 (3-term), |eps|<=2.5e-5
__device__ __forceinline__ float gelu_fast(float x) {
    float z = fabsf(x) * 0.70710678118654752f;
    float t = __builtin_amdgcn_rcpf(1.0f + 0.47047f * z);
    float poly = t * (0.3480242f + t * (-0.0958798f + t * 0.7478556f));
    float erfv = 1.0f - poly * __expf(-z * z);
    float s = copysignf(erfv, x);
    return 0.5f * x * (1.0f + s);
}

#define GLOAD_LDS16(g, l)                                                     \
    __builtin_amdgcn_global_load_lds(                                         \
        (const __attribute__((address_space(1))) unsigned int*)(g),           \
        (__attribute__((address_space(3))) unsigned int*)(l), 16, 0, 0)

__device__ __forceinline__ bf16x8 cvt8(float4 a, float4 b) {
    bf16x8 r;
    r[0] = (bf16)a.x; r[1] = (bf16)a.y; r[2] = (bf16)a.z; r[3] = (bf16)a.w;
    r[4] = (bf16)b.x; r[5] = (bf16)b.y; r[6] = (bf16)b.z; r[7] = (bf16)b.w;
    return r;
}

__device__ __forceinline__ void add8(float* a, uint4 v) {
    a[0] += __uint_as_float(v.x << 16);  a[1] += __uint_as_float(v.x & 0xffff0000u);
    a[2] += __uint_as_float(v.y << 16);  a[3] += __uint_as_float(v.y & 0xffff0000u);
    a[4] += __uint_as_float(v.z << 16);  a[5] += __uint_as_float(v.z & 0xffff0000u);
    a[6] += __uint_as_float(v.w << 16);  a[7] += __uint_as_float(v.w & 0xffff0000u);
}

// ---------------------------------------------------------------------------
// k_front: fused [proj | transpose | bucket], parity-interleaved classes.
// ---------------------------------------------------------------------------
__global__ __launch_bounds__(256) void k_front(
    const float* __restrict__ x,
    const float* __restrict__ Wproj, const float* __restrict__ bproj,
    const float* __restrict__ Wx,    const float* __restrict__ bx,
    bf16* __restrict__ pp, bf16* __restrict__ hb,
    const float* __restrict__ WA, bf16* __restrict__ Mb,
    const int* __restrict__ esrc, const int* __restrict__ edst,
    int* __restrict__ gcur, unsigned* __restrict__ pairs,
    int N, int E, int nbuck, int nbP, int nbT)
{
    __shared__ alignas(16) char smem[33280];
    const int tid = threadIdx.x;

    const int bid = blockIdx.x;
    const int two = 2 * nbP;
    int cls, idx;
    if (bid < two) { cls = bid & 1; idx = bid >> 1; }
    else           { cls = 1; idx = nbP + (bid - two); }

    if (cls == 0) {
        // ---------------- proj ----------------
        bf16* x_s = (bf16*)smem;                 // [64][136]
        const int w = tid >> 6, l = tid & 63;
        const int c = l & 15, g = l >> 4;

        bf16x8 bfr[3][4];
        float bias[3];
        #pragma unroll
        for (int t = 0; t < 3; ++t) {
            int ch = (w * 3 + t) * 16 + c;
            const float* wr = (ch < NPH) ? &Wproj[(size_t)ch * NF]
                                         : &Wx[(size_t)(ch - NPH) * NF];
            bias[t] = (ch < NPH) ? bproj[ch] : bx[ch - NPH];
            #pragma unroll
            for (int ks = 0; ks < 4; ++ks) {
                const float* src = wr + ks * 32 + g * 8;
                bfr[t][ks] = cvt8(*(const float4*)src, *(const float4*)(src + 4));
            }
        }

        const int n0 = idx * 64;
        #pragma unroll
        for (int rr = 0; rr < 8; ++rr) {
            int id  = rr * 256 + tid;
            int row = id >> 5, c4 = id & 31;
            float4 v = make_float4(0.f, 0.f, 0.f, 0.f);
            if (n0 + row < N) v = *(const float4*)&x[(size_t)(n0 + row) * NF + c4 * 4];
            bf16x4 o;
            o[0] = (bf16)v.x; o[1] = (bf16)v.y; o[2] = (bf16)v.z; o[3] = (bf16)v.w;
            *(bf16x4*)&x_s[row * 136 + c4 * 4] = o;
        }
        __syncthreads();

        f32x4 acc[4][3] = {};
        #pragma unroll
        for (int rt = 0; rt < 4; ++rt)
            #pragma unroll
            for (int ks = 0; ks < 4; ++ks) {
                bf16x8 a = *(const bf16x8*)&x_s[(rt * 16 + c) * 136 + ks * 32 + g * 8];
                #pragma unroll
                for (int t = 0; t < 3; ++t)
                    acc[rt][t] = __builtin_amdgcn_mfma_f32_16x16x32_bf16(
                        a, bfr[t][ks], acc[rt][t], 0, 0, 0);
            }

        #pragma unroll
        for (int rt = 0; rt < 4; ++rt) {
            #pragma unroll
            for (int t = 0; t < 3; ++t) {
                int ch = (w * 3 + t) * 16 + c;
                #pragma unroll
                for (int i = 0; i < 4; ++i) {
                    int n = n0 + rt * 16 + g * 4 + i;
                    if (n >= N) continue;
                    float v = acc[rt][t][i] + bias[t];
                    if (ch < NPH) pp[(size_t)n * NPH + ch] = (bf16)v;
                    else          hb[(size_t)n * NH + (ch - NPH)] = (bf16)gelu_fast(v);
                }
            }
        }
    } else if (idx < nbT) {
        // ---------------- transpose ----------------
        float* tt = (float*)smem;                // [128][65]
        const int n0 = idx * 64;
        const int w = tid >> 6, l = tid & 63;
        #pragma unroll
        for (int rep = 0; rep < 32; ++rep) {
            int hh = rep * 4 + w;
            int n  = n0 + l;
            tt[hh * 65 + l] = (n < N) ? WA[(size_t)hh * N + n] : 0.f;
        }
        __syncthreads();
        #pragma unroll
        for (int rep = 0; rep < 32; ++rep) {
            int n_l = rep * 2 + (tid >> 7);
            int n   = n0 + n_l;
            if (n < N) Mb[(size_t)n * NH + (tid & 127)] = (bf16)tt[(tid & 127) * 65 + n_l];
        }
    } else {
        // ---------------- bucket (2-pass, tile 4096 edges) ----------------
        int* cnt  = (int*)smem;          // [<=800]
        int* bofs = cnt + 800;
        const int tile = (idx - nbT) * 4096;
        for (int i = tid; i < nbuck; i += 256) cnt[i] = 0;
        __syncthreads();
        #pragma unroll
        for (int k = 0; k < 16; ++k) {
            int i = tile + k * 256 + tid;
            if (i < E) atomicAdd(&cnt[esrc[i] >> 6], 1);
        }
        __syncthreads();
        for (int i = tid; i < nbuck; i += 256) {
            int c = cnt[i];
            bofs[i] = c ? atomicAdd(&gcur[i], c) : 0;
            cnt[i] = 0;
        }
        __syncthreads();
        #pragma unroll
        for (int k = 0; k < 16; ++k) {
            int i = tile + k * 256 + tid;
            if (i < E) {
                int s = esrc[i], b = s >> 6;
                int r = atomicAdd(&cnt[b], 1);
                pairs[(size_t)b * BCAP + bofs[b] + r] =
                    ((unsigned)(s & 63) << 16) | (unsigned)edst[i];
            }
        }
    }
}

// ---------------------------------------------------------------------------
// k_mid2: fused [ax | path], parity-interleaved, launch_bounds(256,3).
// Path: single barrier per round — ep2 (softmax+write) of round r deferred
// into round r+1's body (s_red double-buffered; pi/hv carried in registers).
// ---------------------------------------------------------------------------
__global__ __launch_bounds__(256, 3) void k_mid2(
    const unsigned* __restrict__ pairs, const int* __restrict__ gcur,
    const bf16* __restrict__ Mb, const float* __restrict__ bA,
    bf16* __restrict__ axbuf2,
    const bf16* __restrict__ pp, const bf16* __restrict__ hb,
    const float* __restrict__ Wpath, const float* __restrict__ bpath,
    const int* __restrict__ index, bf16* __restrict__ aggbuf,
    int N, int E, int nbuck, int nrounds)
{
    __shared__ alignas(16) char smem[35840];
    const int tid = threadIdx.x;

    // interleave: bid<2*nbuck: odd->ax, even->path; tail->path
    const int bid = blockIdx.x;
    const int two = 2 * nbuck;
    int cls, idx;
    if (bid < two) { cls = bid & 1; idx = bid >> 1; }
    else           { cls = 0; idx = nbuck + (bid - two); }

    if (cls == 1) {
        // ---------------- ax: in-LDS sort + gather (bucket idx) ----------------
        int* hist  = (int*)smem;                       // [64]
        int* sc    = hist + 64;                        // [64] inclusive scan
        int* cur   = hist + 128;                       // [64]
        unsigned short* dstl = (unsigned short*)(smem + 768);  // [BCAP]
        const int b = idx, t = tid;
        const int cnt = gcur[b];
        const unsigned* pb = pairs + (size_t)b * BCAP;

        if (t < 64) hist[t] = 0;
        __syncthreads();
        for (int j = t; j < cnt; j += 256)
            atomicAdd(&hist[pb[j] >> 16], 1);
        __syncthreads();
        if (t < 64) sc[t] = hist[t];
        __syncthreads();
        for (int off = 1; off < 64; off <<= 1) {
            int u = (t < 64 && t >= off) ? sc[t - off] : 0;
            __syncthreads();
            if (t < 64) sc[t] += u;
            __syncthreads();
        }
        if (t < 64) cur[t] = sc[t] - hist[t];          // exclusive base
        __syncthreads();
        for (int j = t; j < cnt; j += 256) {
            unsigned p = pb[j];
            int pos = atomicAdd(&cur[p >> 16], 1);
            dstl[pos] = (unsigned short)(p & 0xffffu);
        }
        __syncthreads();

        // gather: wave w handles nodes w, w+4, ... (16 per wave)
        const int w = t >> 6, l = t & 63;
        const int e = l >> 4, q = l & 15;
        const unsigned short* Mu = (const unsigned short*)Mb;
        const int nb0 = b * 64;
        #pragma unroll 1
        for (int it = 0; it < 16; ++it) {
            const int node = it * 4 + w;
            const int n = nb0 + node;
            const int le = sc[node];
            int j = le - hist[node];
            float acc[8] = {0.f, 0.f, 0.f, 0.f, 0.f, 0.f, 0.f, 0.f};
            for (; j + 32 <= le; j += 32) {
                int d[8];
                #pragma unroll
                for (int k = 0; k < 8; ++k) d[k] = dstl[j + k * 4 + e];
                uint4 v[8];
                #pragma unroll
                for (int k = 0; k < 8; ++k)
                    v[k] = *((const uint4*)(Mu + (size_t)d[k] * NH) + q);
                #pragma unroll
                for (int k = 0; k < 8; ++k) add8(acc, v[k]);
            }
            for (; j + 4 <= le; j += 4) {
                int d0 = dstl[j + e];
                uint4 v0 = *((const uint4*)(Mu + (size_t)d0 * NH) + q);
                add8(acc, v0);
            }
            if (e < le - j) {
                int d0 = dstl[j + e];
                uint4 v0 = *((const uint4*)(Mu + (size_t)d0 * NH) + q);
                add8(acc, v0);
            }
            #pragma unroll
            for (int k = 0; k < 8; ++k) {
                acc[k] += __shfl_xor(acc[k], 16, 64);
                acc[k] += __shfl_xor(acc[k], 32, 64);
            }
            if (l < 16 && n < N) {
                float4 bA0 = *(const float4*)&bA[q * 8];
                float4 bA1 = *(const float4*)&bA[q * 8 + 4];
                bf16x8 o;
                o[0] = (bf16)(0.5f * (acc[0] + bA0.x));
                o[1] = (bf16)(0.5f * (acc[1] + bA0.y));
                o[2] = (bf16)(0.5f * (acc[2] + bA0.z));
                o[3] = (bf16)(0.5f * (acc[3] + bA0.w));
                o[4] = (bf16)(0.5f * (acc[4] + bA1.x));
                o[5] = (bf16)(0.5f * (acc[5] + bA1.y));
                o[6] = (bf16)(0.5f * (acc[6] + bA1.z));
                o[7] = (bf16)(0.5f * (acc[7] + bA1.w));
                *(bf16x8*)&axbuf2[(size_t)n * NH + q * 8] = o;
            }
        }
        return;
    }

    // ---------------- path (deferred-ep2, 1 barrier/round) ----------
    bf16*  path_s = (bf16*)smem;                 // [2][32*256]  32768 B
    bf16*  h_sb   = (bf16*)(smem + 32768);       // [2][4][128]   2048 B
    float* s_red  = (float*)(smem + 34816);      // [2][4][32]   1024 B

    const int w   = tid >> 6;
    const int l   = tid & 63;
    const int c   = l & 15;
    const int g   = l >> 4;
    const int nl  = g >> 1;            // local node (within a pair)

    bf16x8 bfrag[2][8];
    #pragma unroll
    for (int ht = 0; ht < 2; ++ht) {
        int hg = (w * 2 + ht) * 16 + c;
        #pragma unroll
        for (int ks = 0; ks < 8; ++ks) {
            const float* src = &Wpath[(size_t)hg * 256 + ks * 32 + g * 8];
            bfrag[ht][ks] = cvt8(*(const float4*)src, *(const float4*)(src + 4));
        }
    }
    const float bp0 = bpath[(w * 2 + 0) * 16 + c];
    const float bp1 = bpath[(w * 2 + 1) * 16 + c];

    auto stage = [&](int round, int b) {
        const int n0 = round * 4;
        #pragma unroll
        for (int rr = 0; rr < 4; ++rr) {
            int id  = rr * 256 + tid;
            int row = id >> 5;
            int cc  = id & 31;
            int ls  = cc ^ (row & 7);      // source-side swizzle
            int d   = ls >> 3, q = ls & 7;
            int nn  = row >> 3, p = row & 7;
            int idx2 = index[(size_t)(n0 + nn) * (NP * ND) + p * ND + d];
            GLOAD_LDS16(pp + (size_t)idx2 * NPH + q * 8, &path_s[b * 8192 + id * 8]);
        }
        if (tid < 64) {
            int node = tid >> 4, q = tid & 15;   // 4 nodes x 16 chunks of 8 bf16
            GLOAD_LDS16(hb + (size_t)(n0 + node) * NH + q * 8,
                        &h_sb[(b * 4 + node) * 128 + q * 8]);
        }
    };

    // deferred-ep2: softmax + aggregate + store for round described by
    // (pi_p, hvs_p, n0_p), reading s_red buffer sbp.
    auto ep2 = [&](const float pi_p[2][2][4], const float hvs_p[2][2],
                   int n0_p, int sbp) {
        #pragma unroll
        for (int rt = 0; rt < 2; ++rt) {
            const float* sr = &s_red[sbp * 128];
            float4 r0 = *(const float4*)&sr[0 * 32 + rt * 16 + g * 4];
            float4 r1 = *(const float4*)&sr[1 * 32 + rt * 16 + g * 4];
            float4 r2 = *(const float4*)&sr[2 * 32 + rt * 16 + g * 4];
            float4 r3 = *(const float4*)&sr[3 * 32 + rt * 16 + g * 4];
            float st[4];
            st[0] = r0.x + r1.x + r2.x + r3.x;
            st[1] = r0.y + r1.y + r2.y + r3.y;
            st[2] = r0.z + r1.z + r2.z + r3.z;
            st[3] = r0.w + r1.w + r2.w + r3.w;
            float m4 = fmaxf(fmaxf(st[0], st[1]), fmaxf(st[2], st[3]));
            float m  = fmaxf(m4, __shfl_xor(m4, 16, 64));
            float e[4], s4 = 0.f;
            #pragma unroll
            for (int i = 0; i < 4; ++i) { e[i] = __expf(st[i] - m); s4 += e[i]; }
            float den = s4 + __shfl_xor(s4, 16, 64);
            const float inv = __builtin_amdgcn_rcpf(den);

            float pa0 = 0.f, pa1 = 0.f;
            #pragma unroll
            for (int i = 0; i < 4; ++i) {
                pa0 += e[i] * pi_p[rt][0][i];
                pa1 += e[i] * pi_p[rt][1][i];
            }
            pa0 = (pa0 + __shfl_xor(pa0, 16, 64)) * inv;
            pa1 = (pa1 + __shfl_xor(pa1, 16, 64)) * inv;

            if (!(g & 1)) {
                int n = n0_p + rt * 2 + nl;
                aggbuf[(size_t)n * NH + w * 32 + c]      = (bf16)(0.5f * (pa0 + hvs_p[rt][0]));
                aggbuf[(size_t)n * NH + w * 32 + 16 + c] = (bf16)(0.5f * (pa1 + hvs_p[rt][1]));
            }
        }
    };

    int r = idx;
    const int G = gridDim.x - nbuck;  // NPATH
    if (r < nrounds) stage(r, 0);
    int buf = 0, sb = 0;
    float pi_p[2][2][4];
    float hvs_p[2][2];
    int n0_p = 0;
    bool have = false;

    for (; r < nrounds; r += G) {
        const int n0 = r * 4;
        __syncthreads();   // stage(r) complete + prev ep1 s_red writes visible
        if (r + G < nrounds) stage(r + G, buf ^ 1);   // prefetch next round

        // deferred ep2 for the previous round (overlaps with MFMA below)
        if (have) ep2(pi_p, hvs_p, n0_p, sb ^ 1);

        f32x4 acc[2][2] = {};
        #pragma unroll
        for (int rt = 0; rt < 2; ++rt) {
            const int rowbase = buf * 8192 + (rt * 16 + c) * 256;
            #pragma unroll
            for (int ks = 0; ks < 8; ++ks) {
                int chunk = (ks * 4 + g) ^ (c & 7);     // read-side XOR
                bf16x8 a = *(const bf16x8*)&path_s[rowbase + chunk * 8];
                acc[rt][0] = __builtin_amdgcn_mfma_f32_16x16x32_bf16(
                    a, bfrag[0][ks], acc[rt][0], 0, 0, 0);
                acc[rt][1] = __builtin_amdgcn_mfma_f32_16x16x32_bf16(
                    a, bfrag[1][ks], acc[rt][1], 0, 0, 0);
            }
        }

        // ep1: pi = gelu(acc+b); capture hv; row-sums via DPP -> s_red[sb]
        #pragma unroll
        for (int rt = 0; rt < 2; ++rt) {
            const float hv0 = (float)h_sb[(buf * 4 + rt * 2 + nl) * 128 + w * 32 + c];
            const float hv1 = (float)h_sb[(buf * 4 + rt * 2 + nl) * 128 + w * 32 + 16 + c];
            hvs_p[rt][0] = hv0; hvs_p[rt][1] = hv1;
            float sp[4];
            #pragma unroll
            for (int i = 0; i < 4; ++i) {
                pi_p[rt][0][i] = gelu_fast(acc[rt][0][i] + bp0);
                pi_p[rt][1][i] = gelu_fast(acc[rt][1][i] + bp1);
                sp[i] = hv0 * pi_p[rt][0][i] + hv1 * pi_p[rt][1][i];
            }
            #pragma unroll
            for (int i = 0; i < 4; ++i) sp[i] = row16_sum(sp[i]);
            float v = (c == 0) ? sp[0] : (c == 1) ? sp[1] : (c == 2) ? sp[2] : sp[3];
            if (c < 4) s_red[sb * 128 + w * 32 + rt * 16 + g * 4 + c] = v;
        }

        n0_p = n0;
        have = true;
        sb ^= 1;
        buf ^= 1;
    }

    // flush the final round's ep2
    if (have) {
        __syncthreads();
        ep2(pi_p, hvs_p, n0_p, sb ^ 1);
    }
}

// ---------------------------------------------------------------------------
// k_fin: out = gelu(aggbuf + axbuf2) @ Wend.T + bend  (bf16 in, ~32 MB total)
// ---------------------------------------------------------------------------
__global__ __launch_bounds__(256) void k_fin(
    const bf16* __restrict__ aggbuf, const bf16* __restrict__ axbuf2,
    const float* __restrict__ Wend, const float* __restrict__ bend,
    float* __restrict__ out, int N)
{
    __shared__ float wend_s[NC][128];
    __shared__ float bend_s[NC];
    const int tid = threadIdx.x;
    for (int id = tid; id < NC * 128; id += 256) wend_s[id >> 7][id & 127] = Wend[id];
    if (tid < NC) bend_s[tid] = bend[tid];
    __syncthreads();

    const int w = tid >> 6, l = tid & 63;
    const int n = blockIdx.x * 4 + w;
    if (n >= N) return;
    const int q = l & 15;

    bf16x8 ag = *(const bf16x8*)&aggbuf[(size_t)n * NH + q * 8];
    bf16x8 ax = *(const bf16x8*)&axbuf2[(size_t)n * NH + q * 8];
    float gg[8];
    #pragma unroll
    for (int k = 0; k < 8; ++k)
        gg[k] = gelu_fast((float)ag[k] + (float)ax[k]);

    float part[NC];
    #pragma unroll
    for (int cc = 0; cc < NC; ++cc) {
        float p = 0.f;
        #pragma unroll
        for (int k = 0; k < 8; ++k) p += gg[k] * wend_s[cc][q * 8 + k];
        part[cc] = row16_sum(p);
    }

    float r = part[0];
    #pragma unroll
    for (int cc = 1; cc < NC; ++cc) r = (l == cc) ? part[cc] : r;
    if (l < NC) out[(size_t)n * NC + l] = r + bend_s[l];
}

// ---------------------------------------------------------------------------
extern "C" void kernel_launch(void* const* d_in, const int* in_sizes, int n_in,
                              void* d_out, int out_size, void* d_ws, size_t ws_size,
                              hipStream_t stream)
{
    const float* x     = (const float*)d_in[0];
    const float* Wproj = (const float*)d_in[1];
    const float* bproj = (const float*)d_in[2];
    const float* Wx    = (const float*)d_in[3];
    const float* bx    = (const float*)d_in[4];
    const float* Wpath = (const float*)d_in[5];
    const float* bpath = (const float*)d_in[6];
    const float* WA    = (const float*)d_in[7];
    const float* bA    = (const float*)d_in[8];
    const float* Wend  = (const float*)d_in[9];
    const float* bend  = (const float*)d_in[10];
    const int*   index = (const int*)d_in[11];
    const int*   eidx  = (const int*)d_in[12];

    const int N = in_sizes[0] / NF;
    const int E = in_sizes[12] / 2;
    const int* esrc = eidx;
    const int* edst = eidx + E;
    const int nbuck = (N + 63) >> 6;     // 64-node buckets (needs N <= 65536)

    char* p = (char*)d_ws;
    auto alloc = [&](size_t bytes) {
        char* r = p;
        p += (bytes + 255) & ~(size_t)255;
        return r;
    };
    bf16*     pp     = (bf16*)alloc((size_t)N * NPH * sizeof(bf16));
    bf16*     hb     = (bf16*)alloc((size_t)N * NH * sizeof(bf16));
    bf16*     aggbuf = (bf16*)alloc((size_t)N * NH * sizeof(bf16));
    bf16*     axbuf2 = (bf16*)alloc((size_t)N * NH * sizeof(bf16));
    bf16*     Mb     = (bf16*)alloc((size_t)N * NH * sizeof(bf16));
    unsigned* pairs  = (unsigned*)alloc((size_t)nbuck * BCAP * sizeof(unsigned));
    int*      gcur   = (int*)alloc((size_t)nbuck * sizeof(int));

    const int nbP = (N + 63) / 64;
    const int nbT = (N + 63) / 64;
    const int nbB = (E + 4095) / 4096;
    const int NPATH = 1024;
    const int nrounds = N / 4;

    hipMemsetAsync(gcur, 0, (size_t)nbuck * sizeof(int), stream);
    k_front<<<nbP + nbT + nbB, 256, 0, stream>>>(
        x, Wproj, bproj, Wx, bx, pp, hb, WA, Mb, esrc, edst, gcur, pairs,
        N, E, nbuck, nbP, nbT);
    k_mid2<<<nbuck + NPATH, 256, 0, stream>>>(
        pairs, gcur, Mb, bA, axbuf2, pp, hb, Wpath, bpath, index, aggbuf,
        N, E, nbuck, nrounds);
    k_fin<<<(N + 3) / 4, 256, 0, stream>>>(aggbuf, axbuf2, Wend, bend,
                                           (float*)d_out, N);
}